// Round 16
// baseline (1188.591 us; speedup 1.0000x reference)
//
#include <hip/hip_runtime.h>

#define NN 20000
#define NE 320000
#define D 128
#define LAYERS 3
#define BN_EPS 1e-5f

typedef __attribute__((ext_vector_type(8))) short s16x8;
typedef __attribute__((ext_vector_type(4))) float f32x4;

__device__ __forceinline__ float sigm_(float x) { return 1.0f / (1.0f + __expf(-x)); }
__device__ __forceinline__ float silu_(float x) { return x * sigm_(x); }
__device__ __forceinline__ float bf2f(unsigned short u) {
    union { unsigned int u; float f; } v; v.u = ((unsigned int)u) << 16; return v.f;
}
__device__ __forceinline__ unsigned short f2bf(float f) {
    union { float f; unsigned int u; } v; v.f = f;
    return (unsigned short)((v.u + 0x7FFFu + ((v.u >> 16) & 1u)) >> 16);
}

#define SWT_STRIDE 136

// ---------- all weight conversions in one dispatch: blockIdx.y = job
struct ConvJobs {
    const float* W[17];
    unsigned short* Hi[17];
    unsigned short* Lo[17];  // nullptr => single bf16 convert
};
__global__ __launch_bounds__(256) void conv_all_kernel(ConvJobs jobs)
{
    int y = blockIdx.y;
    int idx = blockIdx.x * 256 + threadIdx.x;  // 16384
    int k = idx >> 7, n = idx & 127;
    float v = jobs.W[y][idx];
    unsigned short hi = f2bf(v);
    jobs.Hi[y][n * 128 + k] = hi;
    if (jobs.Lo[y]) jobs.Lo[y][n * 128 + k] = f2bf(v - bf2f(hi));
}

struct MatsB2 {
    const unsigned short* WThi[4];
    const unsigned short* WTlo[4];
    const float* b[4];
    float* C[4];
};

// ---------- split-precision MFMA node matmul
__global__ __launch_bounds__(256, 2) void mfmm_node_kernel(
    const unsigned short* __restrict__ Ahi, const unsigned short* __restrict__ Alo,
    int M, MatsB2 ms)
{
    __shared__ unsigned short sW[128 * SWT_STRIDE];
    const int mat = blockIdx.y;
    const unsigned short* __restrict__ WThi = ms.WThi[mat];
    const unsigned short* __restrict__ WTlo = ms.WTlo[mat];
    const float* __restrict__ bias = ms.b[mat];
    float* __restrict__ C = ms.C[mat];
    const int t = threadIdx.x;
    const int w = t >> 6, lane = t & 63;
    const int q = lane >> 4, n = lane & 15;
    const int row0 = blockIdx.x * 128;

    int r0 = row0 + w * 32 + n;      if (r0 >= M) r0 = M - 1;
    int r1 = row0 + w * 32 + 16 + n; if (r1 >= M) r1 = M - 1;
    const size_t o0 = (size_t)r0 * D + q * 8;
    const size_t o1 = (size_t)r1 * D + q * 8;

    s16x8 ah[2][4], al[2][4];
#pragma unroll
    for (int kk = 0; kk < 4; ++kk) {
        ah[0][kk] = *(const s16x8*)(Ahi + o0 + kk * 32);
        ah[1][kk] = *(const s16x8*)(Ahi + o1 + kk * 32);
        al[0][kk] = *(const s16x8*)(Alo + o0 + kk * 32);
        al[1][kk] = *(const s16x8*)(Alo + o1 + kk * 32);
    }

    f32x4 acc[2][8];
#pragma unroll
    for (int tm = 0; tm < 2; ++tm)
#pragma unroll
        for (int tc = 0; tc < 8; ++tc) acc[tm][tc] = (f32x4){0.f, 0.f, 0.f, 0.f};

    // pass 1: W_hi (a_hi + a_lo)
#pragma unroll
    for (int i = 0; i < 8; ++i) {
        int flat = t * 8 + i * 2048;
        int r = flat >> 7, k = flat & 127;
        *(s16x8*)&sW[r * SWT_STRIDE + k] = *(const s16x8*)(WThi + flat);
    }
    __syncthreads();
#pragma unroll
    for (int kk = 0; kk < 4; ++kk) {
#pragma unroll
        for (int tc = 0; tc < 8; ++tc) {
            s16x8 bf = *(const s16x8*)&sW[(tc * 16 + n) * SWT_STRIDE + kk * 32 + q * 8];
            acc[0][tc] = __builtin_amdgcn_mfma_f32_16x16x32_bf16(ah[0][kk], bf, acc[0][tc], 0, 0, 0);
            acc[1][tc] = __builtin_amdgcn_mfma_f32_16x16x32_bf16(ah[1][kk], bf, acc[1][tc], 0, 0, 0);
            acc[0][tc] = __builtin_amdgcn_mfma_f32_16x16x32_bf16(al[0][kk], bf, acc[0][tc], 0, 0, 0);
            acc[1][tc] = __builtin_amdgcn_mfma_f32_16x16x32_bf16(al[1][kk], bf, acc[1][tc], 0, 0, 0);
        }
    }
    __syncthreads();

    // pass 2: W_lo (a_hi only)
#pragma unroll
    for (int i = 0; i < 8; ++i) {
        int flat = t * 8 + i * 2048;
        int r = flat >> 7, k = flat & 127;
        *(s16x8*)&sW[r * SWT_STRIDE + k] = *(const s16x8*)(WTlo + flat);
    }
    __syncthreads();
#pragma unroll
    for (int kk = 0; kk < 4; ++kk) {
#pragma unroll
        for (int tc = 0; tc < 8; ++tc) {
            s16x8 bf = *(const s16x8*)&sW[(tc * 16 + n) * SWT_STRIDE + kk * 32 + q * 8];
            acc[0][tc] = __builtin_amdgcn_mfma_f32_16x16x32_bf16(ah[0][kk], bf, acc[0][tc], 0, 0, 0);
            acc[1][tc] = __builtin_amdgcn_mfma_f32_16x16x32_bf16(ah[1][kk], bf, acc[1][tc], 0, 0, 0);
        }
    }

    float bs[8];
#pragma unroll
    for (int tc = 0; tc < 8; ++tc) bs[tc] = bias[tc * 16 + n];

#pragma unroll
    for (int tm = 0; tm < 2; ++tm)
#pragma unroll
        for (int r = 0; r < 4; ++r) {
            int row = row0 + w * 32 + tm * 16 + q * 4 + r;
            if (row >= M) continue;
#pragma unroll
            for (int tc = 0; tc < 8; ++tc)
                C[(size_t)row * D + tc * 16 + n] = acc[tm][tc][r] + bs[tc];
        }
}

// ---------- fused final MLP (dual LDS, 2 blocks/CU, e pre-updated by agg_apply)
__global__ __launch_bounds__(256, 2) void mfmm_final_kernel(
    const unsigned short* __restrict__ E,
    const unsigned short* __restrict__ WT1, const float* __restrict__ b1,
    const unsigned short* __restrict__ WT2, const float* __restrict__ b2,
    const float* __restrict__ f3w, const float* __restrict__ f3b,
    float* __restrict__ out, const int* __restrict__ perm)
{
    __shared__ unsigned short sW1[128 * SWT_STRIDE];
    __shared__ unsigned short sW2[128 * SWT_STRIDE];
    const int t = threadIdx.x;
    const int w = t >> 6, lane = t & 63;
    const int q = lane >> 4, n = lane & 15;
    const int row0 = blockIdx.x * 128;

#pragma unroll
    for (int i = 0; i < 8; ++i) {
        int flat = t * 8 + i * 2048;
        int r = flat >> 7, k = flat & 127;
        *(s16x8*)&sW1[r * SWT_STRIDE + k] = *(const s16x8*)(WT1 + flat);
    }
    __syncthreads();

    f32x4 acc[2][8];
#pragma unroll
    for (int tm = 0; tm < 2; ++tm)
#pragma unroll
        for (int tc = 0; tc < 8; ++tc) acc[tm][tc] = (f32x4){0.f, 0.f, 0.f, 0.f};

    const unsigned short* a0p = E + (size_t)(row0 + w * 32 + n) * D + q * 8;

#pragma unroll
    for (int kk = 0; kk < 128; kk += 32) {
        s16x8 af0 = *(const s16x8*)(a0p + kk);
        s16x8 af1 = *(const s16x8*)(a0p + 16 * D + kk);
#pragma unroll
        for (int tc = 0; tc < 8; ++tc) {
            s16x8 bf = *(const s16x8*)&sW1[(tc * 16 + n) * SWT_STRIDE + kk + q * 8];
            acc[0][tc] = __builtin_amdgcn_mfma_f32_16x16x32_bf16(af0, bf, acc[0][tc], 0, 0, 0);
            acc[1][tc] = __builtin_amdgcn_mfma_f32_16x16x32_bf16(af1, bf, acc[1][tc], 0, 0, 0);
        }
    }

    float bs1[8];
#pragma unroll
    for (int tc = 0; tc < 8; ++tc) bs1[tc] = b1[tc * 16 + n];
#pragma unroll
    for (int tm = 0; tm < 2; ++tm)
#pragma unroll
        for (int tc = 0; tc < 8; ++tc)
#pragma unroll
            for (int r = 0; r < 4; ++r) {
                int row = w * 32 + tm * 16 + q * 4 + r;
                int col = tc * 16 + n;
                sW2[row * SWT_STRIDE + col] = f2bf(silu_(acc[tm][tc][r] + bs1[tc]));
            }
    __syncthreads();

#pragma unroll
    for (int i = 0; i < 8; ++i) {
        int flat = t * 8 + i * 2048;
        int r = flat >> 7, k = flat & 127;
        *(s16x8*)&sW1[r * SWT_STRIDE + k] = *(const s16x8*)(WT2 + flat);
    }
    __syncthreads();

#pragma unroll
    for (int tm = 0; tm < 2; ++tm)
#pragma unroll
        for (int tc = 0; tc < 8; ++tc) acc[tm][tc] = (f32x4){0.f, 0.f, 0.f, 0.f};
#pragma unroll
    for (int kk = 0; kk < 128; kk += 32) {
        s16x8 af0 = *(const s16x8*)&sW2[(w * 32 + n) * SWT_STRIDE + kk + q * 8];
        s16x8 af1 = *(const s16x8*)&sW2[(w * 32 + 16 + n) * SWT_STRIDE + kk + q * 8];
#pragma unroll
        for (int tc = 0; tc < 8; ++tc) {
            s16x8 bf = *(const s16x8*)&sW1[(tc * 16 + n) * SWT_STRIDE + kk + q * 8];
            acc[0][tc] = __builtin_amdgcn_mfma_f32_16x16x32_bf16(af0, bf, acc[0][tc], 0, 0, 0);
            acc[1][tc] = __builtin_amdgcn_mfma_f32_16x16x32_bf16(af1, bf, acc[1][tc], 0, 0, 0);
        }
    }

    float bs2[8], f3v[8];
#pragma unroll
    for (int tc = 0; tc < 8; ++tc) {
        bs2[tc] = b2[tc * 16 + n];
        f3v[tc] = f3w[tc * 16 + n];
    }
    __syncthreads();
    float* red = (float*)sW2;  // [128][17]
#pragma unroll
    for (int tm = 0; tm < 2; ++tm)
#pragma unroll
        for (int r = 0; r < 4; ++r) {
            float p = 0.f;
#pragma unroll
            for (int tc = 0; tc < 8; ++tc)
                p = fmaf(silu_(acc[tm][tc][r] + bs2[tc]), f3v[tc], p);
            int row = w * 32 + tm * 16 + q * 4 + r;
            red[row * 17 + n] = p;
        }
    __syncthreads();
    if (t < 128) {
        float s = 0.f;
#pragma unroll
        for (int x = 0; x < 16; ++x) s += red[t * 17 + x];
        out[perm[row0 + t]] = sigm_(s + f3b[0]);
    }
}

// ---------- mfmm_te: t_e = e@Aw + Ab + Bh[psrc] + Ch[pdst] -> T, column stat partials
__global__ __launch_bounds__(256, 4) void mfmm_te_kernel(
    const unsigned short* __restrict__ A,   // e_bf (permuted order)
    const unsigned short* __restrict__ WT,
    const float* __restrict__ bias,
    const float* __restrict__ Bh, const float* __restrict__ Ch,
    const int* __restrict__ psrc, const int* __restrict__ pdst,
    unsigned short* __restrict__ T,
    float* __restrict__ P)
{
    __shared__ unsigned short sW[128 * SWT_STRIDE];
    const int t = threadIdx.x;
    const int w = t >> 6, lane = t & 63;
    const int q = lane >> 4, n = lane & 15;
    const int row0 = blockIdx.x * 128;

#pragma unroll
    for (int i = 0; i < 8; ++i) {
        int flat = t * 8 + i * 2048;
        int r = flat >> 7, k = flat & 127;
        *(s16x8*)&sW[r * SWT_STRIDE + k] = *(const s16x8*)(WT + flat);
    }
    __syncthreads();

    f32x4 acc[2][8];
#pragma unroll
    for (int tm = 0; tm < 2; ++tm)
#pragma unroll
        for (int tc = 0; tc < 8; ++tc) acc[tm][tc] = (f32x4){0.f, 0.f, 0.f, 0.f};

    const unsigned short* a0p = A + (size_t)(row0 + w * 32 + n) * D + q * 8;

#pragma unroll
    for (int kk = 0; kk < 128; kk += 32) {
        s16x8 af0 = *(const s16x8*)(a0p + kk);
        s16x8 af1 = *(const s16x8*)(a0p + 16 * D + kk);
#pragma unroll
        for (int tc = 0; tc < 8; ++tc) {
            s16x8 bf = *(const s16x8*)&sW[(tc * 16 + n) * SWT_STRIDE + kk + q * 8];
            acc[0][tc] = __builtin_amdgcn_mfma_f32_16x16x32_bf16(af0, bf, acc[0][tc], 0, 0, 0);
            acc[1][tc] = __builtin_amdgcn_mfma_f32_16x16x32_bf16(af1, bf, acc[1][tc], 0, 0, 0);
        }
    }

    float bs[8];
#pragma unroll
    for (int tc = 0; tc < 8; ++tc) bs[tc] = bias[tc * 16 + n];

    __syncthreads();
#pragma unroll
    for (int tm = 0; tm < 2; ++tm)
#pragma unroll
        for (int tc = 0; tc < 8; ++tc)
#pragma unroll
            for (int r = 0; r < 4; ++r) {
                int row = w * 32 + tm * 16 + q * 4 + r;
                int col = tc * 16 + n;
                sW[row * SWT_STRIDE + col] = f2bf(acc[tm][tc][r] + bs[tc]);
            }
    __syncthreads();

    const int c4 = (t & 31) * 4;
    const int rg = t >> 5;
    int srs[16], drs[16];
#pragma unroll
    for (int i = 0; i < 16; ++i) {
        int eid = row0 + rg + i * 8;
        srs[i] = psrc[eid];
        drs[i] = pdst[eid];
    }
    float s1[4] = {0.f, 0.f, 0.f, 0.f}, s2[4] = {0.f, 0.f, 0.f, 0.f};
#pragma unroll 4
    for (int i = 0; i < 16; ++i) {
        int row = rg + i * 8;
        int eid = row0 + row;
        float4 bv = *(const float4*)(Bh + (size_t)srs[i] * D + c4);
        float4 cv = *(const float4*)(Ch + (size_t)drs[i] * D + c4);
        ushort4 av = *(const ushort4*)&sW[row * SWT_STRIDE + c4];
        float t0 = bf2f(av.x) + bv.x + cv.x;
        float t1 = bf2f(av.y) + bv.y + cv.y;
        float t2 = bf2f(av.z) + bv.z + cv.z;
        float t3 = bf2f(av.w) + bv.w + cv.w;
        *(ushort4*)(T + (size_t)eid * D + c4) =
            make_ushort4(f2bf(t0), f2bf(t1), f2bf(t2), f2bf(t3));
        s1[0] += t0; s2[0] = fmaf(t0, t0, s2[0]);
        s1[1] += t1; s2[1] = fmaf(t1, t1, s2[1]);
        s1[2] += t2; s2[2] = fmaf(t2, t2, s2[2]);
        s1[3] += t3; s2[3] = fmaf(t3, t3, s2[3]);
    }
    __syncthreads();
    float* red = (float*)sW;
#pragma unroll
    for (int j = 0; j < 4; ++j) {
        red[rg * 128 + c4 + j] = s1[j];
        red[1024 + rg * 128 + c4 + j] = s2[j];
    }
    __syncthreads();
    if (t < 128) {
        float a = 0.f, b = 0.f;
#pragma unroll
        for (int g = 0; g < 8; ++g) { a += red[g * 128 + t]; b += red[1024 + g * 128 + t]; }
        P[(size_t)blockIdx.x * 256 + t] = a;
        P[(size_t)blockIdx.x * 256 + 128 + t] = b;
    }
}

// ---------- fused gather agg + apply_e + t_h column stats (no scatter atomics; wave=node)
// lane -> 4 cols, two half-waves interleave edges; statsH accumulated via LDS + atomicAdd.
__global__ __launch_bounds__(256) void agg_apply_kernel(
    unsigned short* E, const unsigned short* __restrict__ T,
    const float* __restrict__ Vh, const float* __restrict__ stats,
    const int* __restrict__ rowptr, const int* __restrict__ pdst,
    const float* __restrict__ inv_cnt, float* __restrict__ Uh,
    float* __restrict__ statsH)
{
    __shared__ float red[4][256];
    const int wv = threadIdx.x >> 6;
    const int n = blockIdx.x * 4 + wv;
    const int lane = threadIdx.x & 63;
    const int c4 = (lane & 31) * 4;
    const int half = lane >> 5;
    const bool valid = (n < NN);

    float4 sc = *(const float4*)(stats + 2 * D + c4);
    float4 sh = *(const float4*)(stats + 3 * D + c4);

    int beg = 0, end = 0;
    if (valid) { beg = rowptr[n]; end = rowptr[n + 1]; }

    float a0 = 0.f, a1 = 0.f, a2 = 0.f, a3 = 0.f;
    for (int j = beg + half; j < end; j += 2) {
        int g = pdst[j];
        ushort4 ev = *(const ushort4*)(E + (size_t)j * D + c4);
        float4 vv = *(const float4*)(Vh + (size_t)g * D + c4);
        float e0 = bf2f(ev.x), e1 = bf2f(ev.y), e2 = bf2f(ev.z), e3 = bf2f(ev.w);
        a0 = fmaf(sigm_(e0), vv.x, a0);
        a1 = fmaf(sigm_(e1), vv.y, a1);
        a2 = fmaf(sigm_(e2), vv.z, a2);
        a3 = fmaf(sigm_(e3), vv.w, a3);
        ushort4 tv = *(const ushort4*)(T + (size_t)j * D + c4);
        ushort4 o;
        o.x = f2bf(e0 + silu_(fmaf(bf2f(tv.x), sc.x, sh.x)));
        o.y = f2bf(e1 + silu_(fmaf(bf2f(tv.y), sc.y, sh.y)));
        o.z = f2bf(e2 + silu_(fmaf(bf2f(tv.z), sc.z, sh.z)));
        o.w = f2bf(e3 + silu_(fmaf(bf2f(tv.w), sc.w, sh.w)));
        *(ushort4*)(E + (size_t)j * D + c4) = o;
    }
    // merge halves (lane L and L^32 hold the same columns)
    a0 += __shfl_xor(a0, 32);
    a1 += __shfl_xor(a1, 32);
    a2 += __shfl_xor(a2, 32);
    a3 += __shfl_xor(a3, 32);

    if (half == 0) {
        float u0 = 0.f, u1 = 0.f, u2 = 0.f, u3 = 0.f;
        if (valid) {
            float ic = inv_cnt[n];
            float4 u = *(const float4*)(Uh + (size_t)n * D + c4);
            u0 = fmaf(a0, ic, u.x);
            u1 = fmaf(a1, ic, u.y);
            u2 = fmaf(a2, ic, u.z);
            u3 = fmaf(a3, ic, u.w);
            *(float4*)(Uh + (size_t)n * D + c4) = make_float4(u0, u1, u2, u3);
        }
        red[wv][c4 + 0] = u0; red[wv][128 + c4 + 0] = u0 * u0;
        red[wv][c4 + 1] = u1; red[wv][128 + c4 + 1] = u1 * u1;
        red[wv][c4 + 2] = u2; red[wv][128 + c4 + 2] = u2 * u2;
        red[wv][c4 + 3] = u3; red[wv][128 + c4 + 3] = u3 * u3;
    }
    __syncthreads();
    int tt = threadIdx.x;
    float s = red[0][tt] + red[1][tt] + red[2][tt] + red[3][tt];
    atomicAdd(statsH + tt, s);
}

// ---------- stats: partial reduce (no atomics) + merged finalize
__global__ __launch_bounds__(256) void reduceE_kernel(
    const float* __restrict__ P, int nblk, float* __restrict__ P2)
{
    int t = threadIdx.x;
    float s = 0.f;
    for (int j = blockIdx.x; j < nblk; j += gridDim.x)
        s += P[(size_t)j * 256 + t];
    P2[blockIdx.x * 256 + t] = s;
}

__global__ void finalize2_kernel(const float* __restrict__ P, int nblk,
                                 const float* __restrict__ gamma,
                                 const float* __restrict__ beta,
                                 float inv_rows, float* __restrict__ stats)
{
    int c = threadIdx.x;  // 128
    float s1 = 0.f, s2 = 0.f;
    for (int j = 0; j < nblk; ++j) {
        s1 += P[j * 256 + c];
        s2 += P[j * 256 + 128 + c];
    }
    float m = s1 * inv_rows;
    float v = s2 * inv_rows - m * m;
    float rstd = rsqrtf(v + BN_EPS);
    float sc = gamma[c] * rstd;
    stats[2 * D + c] = sc;
    stats[3 * D + c] = beta[c] - m * sc;
}

// ---------- input projections (init_h emits hi/lo too)
__global__ __launch_bounds__(256) void init_h_kernel(
    const float* __restrict__ x, const float* __restrict__ hp_w,
    const float* __restrict__ hp_b, float* __restrict__ h,
    unsigned short* __restrict__ hhi, unsigned short* __restrict__ hlo)
{
    int idx = blockIdx.x * 256 + threadIdx.x;
    int n = idx >> 5, d = (idx & 31) * 4;
    if (n >= NN) return;
    float x0 = x[n * 2], x1 = x[n * 2 + 1];
    float4 w0 = *(const float4*)(hp_w + d);
    float4 w1 = *(const float4*)(hp_w + D + d);
    float4 b = *(const float4*)(hp_b + d);
    float4 o;
    o.x = silu_(fmaf(x0, w0.x, fmaf(x1, w1.x, b.x)));
    o.y = silu_(fmaf(x0, w0.y, fmaf(x1, w1.y, b.y)));
    o.z = silu_(fmaf(x0, w0.z, fmaf(x1, w1.z, b.z)));
    o.w = silu_(fmaf(x0, w0.w, fmaf(x1, w1.w, b.w)));
    *(float4*)(h + (size_t)n * D + d) = o;
    ushort4 hi = make_ushort4(f2bf(o.x), f2bf(o.y), f2bf(o.z), f2bf(o.w));
    ushort4 lo = make_ushort4(f2bf(o.x - bf2f(hi.x)), f2bf(o.y - bf2f(hi.y)),
                              f2bf(o.z - bf2f(hi.z)), f2bf(o.w - bf2f(hi.w)));
    *(ushort4*)(hhi + (size_t)n * D + d) = hi;
    *(ushort4*)(hlo + (size_t)n * D + d) = lo;
}

// init_e in PERMUTED order: row j <- edge eidx[j]
__global__ __launch_bounds__(256) void init_e_kernel(
    const float* __restrict__ ea, const int* __restrict__ eidx,
    const float* __restrict__ ep_w, const float* __restrict__ ep_b,
    unsigned short* __restrict__ e)
{
    int idx = blockIdx.x * 256 + threadIdx.x;
    int j = idx >> 5, d = (idx & 31) * 4;
    if (j >= NE) return;
    float a = ea[eidx[j]];
    float4 w = *(const float4*)(ep_w + d);
    float4 b = *(const float4*)(ep_b + d);
    ushort4 o;
    o.x = f2bf(silu_(fmaf(a, w.x, b.x)));
    o.y = f2bf(silu_(fmaf(a, w.y, b.y)));
    o.z = f2bf(silu_(fmaf(a, w.z, b.z)));
    o.w = f2bf(silu_(fmaf(a, w.w, b.w)));
    *(ushort4*)(e + (size_t)j * D + d) = o;
}

// ---------- CSR build
__global__ __launch_bounds__(256) void deg_kernel(const int* __restrict__ src, int* __restrict__ deg)
{
    int i = blockIdx.x * 256 + threadIdx.x;
    if (i < NE) atomicAdd(&deg[src[i]], 1);
}

__global__ __launch_bounds__(256) void scan_kernel(
    const int* __restrict__ deg, int* __restrict__ rowptr, float* __restrict__ inv_cnt)
{
    __shared__ int chunk[256];
    const int t = threadIdx.x;
    const int CH = (NN + 255) / 256;
    int s = 0;
    for (int i = 0; i < CH; ++i) {
        int idx = t * CH + i;
        if (idx < NN) s += deg[idx];
    }
    chunk[t] = s;
    __syncthreads();
    for (int offs = 1; offs < 256; offs <<= 1) {
        int v = (t >= offs) ? chunk[t - offs] : 0;
        __syncthreads();
        chunk[t] += v;
        __syncthreads();
    }
    int base = (t == 0) ? 0 : chunk[t - 1];
    for (int i = 0; i < CH; ++i) {
        int idx = t * CH + i;
        if (idx < NN) {
            rowptr[idx] = base;
            int d = deg[idx];
            inv_cnt[idx] = 1.0f / fmaxf((float)d, 1.0f);
            base += d;
        }
    }
    if (t == 255) rowptr[NN] = base;
}

__global__ __launch_bounds__(256) void fill_kernel(
    const int* __restrict__ src, const int* __restrict__ dst,
    const int* __restrict__ rowptr, int* __restrict__ cursor,
    int* __restrict__ eidx, int* __restrict__ psrc, int* __restrict__ pdst)
{
    int i = blockIdx.x * 256 + threadIdx.x;
    if (i >= NE) return;
    int s = src[i];
    int p = atomicAdd(&cursor[s], 1);
    int pos = rowptr[s] + p;
    eidx[pos] = i;
    psrc[pos] = s;
    pdst[pos] = dst[i];
}

// h += silu(t_h*sc+sh); also emit h_hi/h_lo for next layer's node matmul
__global__ __launch_bounds__(256) void apply_h_kernel(
    float* __restrict__ h, const float* __restrict__ Th, const float* __restrict__ stats,
    unsigned short* __restrict__ hhi, unsigned short* __restrict__ hlo)
{
    int idx = blockIdx.x * 256 + threadIdx.x;
    int r = idx >> 5, d = (idx & 31) * 4;
    if (r >= NN) return;
    float4 tv = *(const float4*)(Th + (size_t)r * D + d);
    float4 sc = *(const float4*)(stats + 2 * D + d);
    float4 sh = *(const float4*)(stats + 3 * D + d);
    float4 hv = *(const float4*)(h + (size_t)r * D + d);
    hv.x += silu_(fmaf(tv.x, sc.x, sh.x));
    hv.y += silu_(fmaf(tv.y, sc.y, sh.y));
    hv.z += silu_(fmaf(tv.z, sc.z, sh.z));
    hv.w += silu_(fmaf(tv.w, sc.w, sh.w));
    *(float4*)(h + (size_t)r * D + d) = hv;
    ushort4 hi = make_ushort4(f2bf(hv.x), f2bf(hv.y), f2bf(hv.z), f2bf(hv.w));
    ushort4 lo = make_ushort4(f2bf(hv.x - bf2f(hi.x)), f2bf(hv.y - bf2f(hi.y)),
                              f2bf(hv.z - bf2f(hi.z)), f2bf(hv.w - bf2f(hi.w)));
    *(ushort4*)(hhi + (size_t)r * D + d) = hi;
    *(ushort4*)(hlo + (size_t)r * D + d) = lo;
}

extern "C" void kernel_launch(void* const* d_in, const int* in_sizes, int n_in,
                              void* d_out, int out_size, void* d_ws, size_t ws_size,
                              hipStream_t stream)
{
    (void)in_sizes; (void)n_in; (void)out_size;
    const float* x = (const float*)d_in[0];
    const float* edge_attr = (const float*)d_in[1];
    const int* edge_index = (const int*)d_in[2];
    const int* src = edge_index;
    const int* dst = edge_index + NE;
    const float* hp_w = (const float*)d_in[3];
    const float* hp_b = (const float*)d_in[4];
    const float* ep_w = (const float*)d_in[5];
    const float* ep_b = (const float*)d_in[6];
    const float* Uw = (const float*)d_in[7];
    const float* Ub = (const float*)d_in[8];
    const float* Vw = (const float*)d_in[9];
    const float* Vb = (const float*)d_in[10];
    const float* Aw = (const float*)d_in[11];
    const float* Ab = (const float*)d_in[12];
    const float* Bw = (const float*)d_in[13];
    const float* Bb = (const float*)d_in[14];
    const float* Cw = (const float*)d_in[15];
    const float* Cb = (const float*)d_in[16];
    const float* h_gamma = (const float*)d_in[17];
    const float* h_beta = (const float*)d_in[18];
    const float* e_gamma = (const float*)d_in[19];
    const float* e_beta = (const float*)d_in[20];
    const float* f1w = (const float*)d_in[21];
    const float* f1b = (const float*)d_in[22];
    const float* f2w = (const float*)d_in[23];
    const float* f2b = (const float*)d_in[24];
    const float* f3w = (const float*)d_in[25];
    const float* f3b = (const float*)d_in[26];
    float* out = (float*)d_out;

    size_t off = 0;
    auto alloc = [&](size_t nbytes) {
        void* p = (char*)d_ws + off;
        off += ((nbytes + 255) / 256) * 256;
        return p;
    };
    unsigned short* e_bf = (unsigned short*)alloc((size_t)NE * D * 2);
    unsigned short* t_bf = (unsigned short*)alloc((size_t)NE * D * 2);
    float* h  = (float*)alloc((size_t)NN * D * 4);
    unsigned short* h_hi = (unsigned short*)alloc((size_t)NN * D * 2);
    unsigned short* h_lo = (unsigned short*)alloc((size_t)NN * D * 2);
    float* Uh = (float*)alloc((size_t)NN * D * 4);
    float* Vh = (float*)alloc((size_t)NN * D * 4);
    float* Bh = (float*)alloc((size_t)NN * D * 4);
    float* Ch = (float*)alloc((size_t)NN * D * 4);
    int* deg = (int*)alloc(NN * 4);
    int* rowptr = (int*)alloc((NN + 1) * 4);
    int* cursor = (int*)alloc(NN * 4);
    int* eidx = (int*)alloc((size_t)NE * 4);
    int* psrc = (int*)alloc((size_t)NE * 4);
    int* pdst = (int*)alloc((size_t)NE * 4);
    float* inv_cnt = (float*)alloc(NN * 4);
    float* statsH = (float*)alloc(4 * D * 4);
    float* statsE = (float*)alloc(4 * D * 4);
    float* Pstats = (float*)alloc((size_t)(NE / 128) * 256 * 4);
    float* PE2 = (float*)alloc(10 * 256 * 4);
    unsigned short* wtsNhi = (unsigned short*)alloc((size_t)12 * D * D * 2);
    unsigned short* wtsNlo = (unsigned short*)alloc((size_t)12 * D * D * 2);
    unsigned short* wtsE = (unsigned short*)alloc((size_t)5 * D * D * 2);  // A0,A1,A2,F1,F2

    if (off > ws_size) return;  // diagnostic guard

    const int nodeBlocks32 = (NN * 32 + 255) / 256;  // 2500
    const int edgeBlocks32 = (NE * 32) / 256;        // 40000
    const int nodeTiles = (NN + 127) / 128;          // 157
    const int edgeTiles = NE / 128;                  // 2500

    // CSR build (needed before permuted init_e)
    hipMemsetAsync(deg, 0, NN * sizeof(int), stream);
    hipMemsetAsync(cursor, 0, NN * sizeof(int), stream);
    deg_kernel<<<NE / 256, 256, 0, stream>>>(src, deg);
    scan_kernel<<<1, 256, 0, stream>>>(deg, rowptr, inv_cnt);
    fill_kernel<<<NE / 256, 256, 0, stream>>>(src, dst, rowptr, cursor, eidx, psrc, pdst);

    init_h_kernel<<<nodeBlocks32, 256, 0, stream>>>(x, hp_w, hp_b, h, h_hi, h_lo);
    init_e_kernel<<<edgeBlocks32, 256, 0, stream>>>(edge_attr, eidx, ep_w, ep_b, e_bf);

    // all 17 weight conversions in one dispatch
    ConvJobs cj;
    const float* nodeW[4][3] = {{Uw, Uw + 16384, Uw + 32768},
                                {Vw, Vw + 16384, Vw + 32768},
                                {Bw, Bw + 16384, Bw + 32768},
                                {Cw, Cw + 16384, Cw + 32768}};
    for (int l = 0; l < LAYERS; ++l)
        for (int j = 0; j < 4; ++j) {
            int slot = l * 4 + j;
            cj.W[slot] = nodeW[j][l];
            cj.Hi[slot] = wtsNhi + (size_t)slot * D * D;
            cj.Lo[slot] = wtsNlo + (size_t)slot * D * D;
        }
    const float* edgeW[5] = {Aw, Aw + 16384, Aw + 32768, f1w, f2w};
    for (int j = 0; j < 5; ++j) {
        cj.W[12 + j] = edgeW[j];
        cj.Hi[12 + j] = wtsE + (size_t)j * D * D;
        cj.Lo[12 + j] = nullptr;
    }
    conv_all_kernel<<<dim3(64, 17), 256, 0, stream>>>(cj);

    for (int l = 0; l < LAYERS; ++l) {
        const size_t bl = (size_t)l * D;

        MatsB2 m4;
        for (int j = 0; j < 4; ++j) {
            size_t slot = (size_t)(l * 4 + j) * D * D;
            m4.WThi[j] = wtsNhi + slot;
            m4.WTlo[j] = wtsNlo + slot;
        }
        m4.b[0] = Ub + bl; m4.b[1] = Vb + bl; m4.b[2] = Bb + bl; m4.b[3] = Cb + bl;
        m4.C[0] = Uh; m4.C[1] = Vh; m4.C[2] = Bh; m4.C[3] = Ch;
        mfmm_node_kernel<<<dim3(nodeTiles, 4), 256, 0, stream>>>(h_hi, h_lo, NN, m4);

        // t_e matmul + gathers + stat partials
        mfmm_te_kernel<<<edgeTiles, 256, 0, stream>>>(
            e_bf, wtsE + (size_t)l * D * D, Ab + bl, Bh, Ch, psrc, pdst, t_bf, Pstats);

        // e stats
        reduceE_kernel<<<10, 256, 0, stream>>>(Pstats, edgeTiles, PE2);
        finalize2_kernel<<<1, D, 0, stream>>>(PE2, 10, e_gamma + bl, e_beta + bl,
                                              1.0f / NE, statsE);

        // fused aggregation + e-update + t_h column stats (atomic into statsH)
        hipMemsetAsync(statsH, 0, 2 * D * sizeof(float), stream);
        agg_apply_kernel<<<(NN + 3) / 4, 256, 0, stream>>>(
            e_bf, t_bf, Vh, statsE, rowptr, pdst, inv_cnt, Uh, statsH);

        // h update (totals -> finalize -> apply)
        finalize2_kernel<<<1, D, 0, stream>>>(statsH, 1, h_gamma + bl, h_beta + bl,
                                              1.0f / NN, statsH);
        apply_h_kernel<<<nodeBlocks32, 256, 0, stream>>>(h, Uh, statsH, h_hi, h_lo);
    }

    // fused final MLP: f1 + f2 + f3 (e_bf already holds final e state)
    mfmm_final_kernel<<<edgeTiles, 256, 0, stream>>>(
        e_bf,
        wtsE + (size_t)3 * D * D, f1b,
        wtsE + (size_t)4 * D * D, f2b,
        f3w, f3b, out, eidx);
}

// Round 17
// 1064.845 us; speedup vs baseline: 1.1162x; 1.1162x over previous
//
#include <hip/hip_runtime.h>

#define NN 20000
#define NE 320000
#define D 128
#define LAYERS 3
#define BN_EPS 1e-5f

typedef __attribute__((ext_vector_type(8))) short s16x8;
typedef __attribute__((ext_vector_type(4))) float f32x4;

__device__ __forceinline__ float sigm_(float x) { return 1.0f / (1.0f + __expf(-x)); }
__device__ __forceinline__ float silu_(float x) { return x * sigm_(x); }
__device__ __forceinline__ float bf2f(unsigned short u) {
    union { unsigned int u; float f; } v; v.u = ((unsigned int)u) << 16; return v.f;
}
__device__ __forceinline__ unsigned short f2bf(float f) {
    union { float f; unsigned int u; } v; v.f = f;
    return (unsigned short)((v.u + 0x7FFFu + ((v.u >> 16) & 1u)) >> 16);
}

#define SWT_STRIDE 136

// ---------- all weight conversions in one dispatch: blockIdx.y = job
struct ConvJobs {
    const float* W[17];
    unsigned short* Hi[17];
    unsigned short* Lo[17];  // nullptr => single bf16 convert
};
__global__ __launch_bounds__(256) void conv_all_kernel(ConvJobs jobs)
{
    int y = blockIdx.y;
    int idx = blockIdx.x * 256 + threadIdx.x;  // 16384
    int k = idx >> 7, n = idx & 127;
    float v = jobs.W[y][idx];
    unsigned short hi = f2bf(v);
    jobs.Hi[y][n * 128 + k] = hi;
    if (jobs.Lo[y]) jobs.Lo[y][n * 128 + k] = f2bf(v - bf2f(hi));
}

struct MatsB2 {
    const unsigned short* WThi[4];
    const unsigned short* WTlo[4];
    const float* b[4];
    float* C[4];
};

// ---------- split-precision MFMA node matmul
__global__ __launch_bounds__(256, 2) void mfmm_node_kernel(
    const unsigned short* __restrict__ Ahi, const unsigned short* __restrict__ Alo,
    int M, MatsB2 ms)
{
    __shared__ unsigned short sW[128 * SWT_STRIDE];
    const int mat = blockIdx.y;
    const unsigned short* __restrict__ WThi = ms.WThi[mat];
    const unsigned short* __restrict__ WTlo = ms.WTlo[mat];
    const float* __restrict__ bias = ms.b[mat];
    float* __restrict__ C = ms.C[mat];
    const int t = threadIdx.x;
    const int w = t >> 6, lane = t & 63;
    const int q = lane >> 4, n = lane & 15;
    const int row0 = blockIdx.x * 128;

    int r0 = row0 + w * 32 + n;      if (r0 >= M) r0 = M - 1;
    int r1 = row0 + w * 32 + 16 + n; if (r1 >= M) r1 = M - 1;
    const size_t o0 = (size_t)r0 * D + q * 8;
    const size_t o1 = (size_t)r1 * D + q * 8;

    s16x8 ah[2][4], al[2][4];
#pragma unroll
    for (int kk = 0; kk < 4; ++kk) {
        ah[0][kk] = *(const s16x8*)(Ahi + o0 + kk * 32);
        ah[1][kk] = *(const s16x8*)(Ahi + o1 + kk * 32);
        al[0][kk] = *(const s16x8*)(Alo + o0 + kk * 32);
        al[1][kk] = *(const s16x8*)(Alo + o1 + kk * 32);
    }

    f32x4 acc[2][8];
#pragma unroll
    for (int tm = 0; tm < 2; ++tm)
#pragma unroll
        for (int tc = 0; tc < 8; ++tc) acc[tm][tc] = (f32x4){0.f, 0.f, 0.f, 0.f};

    // pass 1: W_hi (a_hi + a_lo)
#pragma unroll
    for (int i = 0; i < 8; ++i) {
        int flat = t * 8 + i * 2048;
        int r = flat >> 7, k = flat & 127;
        *(s16x8*)&sW[r * SWT_STRIDE + k] = *(const s16x8*)(WThi + flat);
    }
    __syncthreads();
#pragma unroll
    for (int kk = 0; kk < 4; ++kk) {
#pragma unroll
        for (int tc = 0; tc < 8; ++tc) {
            s16x8 bf = *(const s16x8*)&sW[(tc * 16 + n) * SWT_STRIDE + kk * 32 + q * 8];
            acc[0][tc] = __builtin_amdgcn_mfma_f32_16x16x32_bf16(ah[0][kk], bf, acc[0][tc], 0, 0, 0);
            acc[1][tc] = __builtin_amdgcn_mfma_f32_16x16x32_bf16(ah[1][kk], bf, acc[1][tc], 0, 0, 0);
            acc[0][tc] = __builtin_amdgcn_mfma_f32_16x16x32_bf16(al[0][kk], bf, acc[0][tc], 0, 0, 0);
            acc[1][tc] = __builtin_amdgcn_mfma_f32_16x16x32_bf16(al[1][kk], bf, acc[1][tc], 0, 0, 0);
        }
    }
    __syncthreads();

    // pass 2: W_lo (a_hi only)
#pragma unroll
    for (int i = 0; i < 8; ++i) {
        int flat = t * 8 + i * 2048;
        int r = flat >> 7, k = flat & 127;
        *(s16x8*)&sW[r * SWT_STRIDE + k] = *(const s16x8*)(WTlo + flat);
    }
    __syncthreads();
#pragma unroll
    for (int kk = 0; kk < 4; ++kk) {
#pragma unroll
        for (int tc = 0; tc < 8; ++tc) {
            s16x8 bf = *(const s16x8*)&sW[(tc * 16 + n) * SWT_STRIDE + kk * 32 + q * 8];
            acc[0][tc] = __builtin_amdgcn_mfma_f32_16x16x32_bf16(ah[0][kk], bf, acc[0][tc], 0, 0, 0);
            acc[1][tc] = __builtin_amdgcn_mfma_f32_16x16x32_bf16(ah[1][kk], bf, acc[1][tc], 0, 0, 0);
        }
    }

    float bs[8];
#pragma unroll
    for (int tc = 0; tc < 8; ++tc) bs[tc] = bias[tc * 16 + n];

#pragma unroll
    for (int tm = 0; tm < 2; ++tm)
#pragma unroll
        for (int r = 0; r < 4; ++r) {
            int row = row0 + w * 32 + tm * 16 + q * 4 + r;
            if (row >= M) continue;
#pragma unroll
            for (int tc = 0; tc < 8; ++tc)
                C[(size_t)row * D + tc * 16 + n] = acc[tm][tc][r] + bs[tc];
        }
}

// ---------- fused final MLP (dual LDS, 2 blocks/CU, e pre-updated by agg_apply)
__global__ __launch_bounds__(256, 2) void mfmm_final_kernel(
    const unsigned short* __restrict__ E,
    const unsigned short* __restrict__ WT1, const float* __restrict__ b1,
    const unsigned short* __restrict__ WT2, const float* __restrict__ b2,
    const float* __restrict__ f3w, const float* __restrict__ f3b,
    float* __restrict__ out, const int* __restrict__ perm)
{
    __shared__ unsigned short sW1[128 * SWT_STRIDE];
    __shared__ unsigned short sW2[128 * SWT_STRIDE];
    const int t = threadIdx.x;
    const int w = t >> 6, lane = t & 63;
    const int q = lane >> 4, n = lane & 15;
    const int row0 = blockIdx.x * 128;

#pragma unroll
    for (int i = 0; i < 8; ++i) {
        int flat = t * 8 + i * 2048;
        int r = flat >> 7, k = flat & 127;
        *(s16x8*)&sW1[r * SWT_STRIDE + k] = *(const s16x8*)(WT1 + flat);
    }
    __syncthreads();

    f32x4 acc[2][8];
#pragma unroll
    for (int tm = 0; tm < 2; ++tm)
#pragma unroll
        for (int tc = 0; tc < 8; ++tc) acc[tm][tc] = (f32x4){0.f, 0.f, 0.f, 0.f};

    const unsigned short* a0p = E + (size_t)(row0 + w * 32 + n) * D + q * 8;

#pragma unroll
    for (int kk = 0; kk < 128; kk += 32) {
        s16x8 af0 = *(const s16x8*)(a0p + kk);
        s16x8 af1 = *(const s16x8*)(a0p + 16 * D + kk);
#pragma unroll
        for (int tc = 0; tc < 8; ++tc) {
            s16x8 bf = *(const s16x8*)&sW1[(tc * 16 + n) * SWT_STRIDE + kk + q * 8];
            acc[0][tc] = __builtin_amdgcn_mfma_f32_16x16x32_bf16(af0, bf, acc[0][tc], 0, 0, 0);
            acc[1][tc] = __builtin_amdgcn_mfma_f32_16x16x32_bf16(af1, bf, acc[1][tc], 0, 0, 0);
        }
    }

    float bs1[8];
#pragma unroll
    for (int tc = 0; tc < 8; ++tc) bs1[tc] = b1[tc * 16 + n];
#pragma unroll
    for (int tm = 0; tm < 2; ++tm)
#pragma unroll
        for (int tc = 0; tc < 8; ++tc)
#pragma unroll
            for (int r = 0; r < 4; ++r) {
                int row = w * 32 + tm * 16 + q * 4 + r;
                int col = tc * 16 + n;
                sW2[row * SWT_STRIDE + col] = f2bf(silu_(acc[tm][tc][r] + bs1[tc]));
            }
    __syncthreads();

#pragma unroll
    for (int i = 0; i < 8; ++i) {
        int flat = t * 8 + i * 2048;
        int r = flat >> 7, k = flat & 127;
        *(s16x8*)&sW1[r * SWT_STRIDE + k] = *(const s16x8*)(WT2 + flat);
    }
    __syncthreads();

#pragma unroll
    for (int tm = 0; tm < 2; ++tm)
#pragma unroll
        for (int tc = 0; tc < 8; ++tc) acc[tm][tc] = (f32x4){0.f, 0.f, 0.f, 0.f};
#pragma unroll
    for (int kk = 0; kk < 128; kk += 32) {
        s16x8 af0 = *(const s16x8*)&sW2[(w * 32 + n) * SWT_STRIDE + kk + q * 8];
        s16x8 af1 = *(const s16x8*)&sW2[(w * 32 + 16 + n) * SWT_STRIDE + kk + q * 8];
#pragma unroll
        for (int tc = 0; tc < 8; ++tc) {
            s16x8 bf = *(const s16x8*)&sW1[(tc * 16 + n) * SWT_STRIDE + kk + q * 8];
            acc[0][tc] = __builtin_amdgcn_mfma_f32_16x16x32_bf16(af0, bf, acc[0][tc], 0, 0, 0);
            acc[1][tc] = __builtin_amdgcn_mfma_f32_16x16x32_bf16(af1, bf, acc[1][tc], 0, 0, 0);
        }
    }

    float bs2[8], f3v[8];
#pragma unroll
    for (int tc = 0; tc < 8; ++tc) {
        bs2[tc] = b2[tc * 16 + n];
        f3v[tc] = f3w[tc * 16 + n];
    }
    __syncthreads();
    float* red = (float*)sW2;  // [128][17]
#pragma unroll
    for (int tm = 0; tm < 2; ++tm)
#pragma unroll
        for (int r = 0; r < 4; ++r) {
            float p = 0.f;
#pragma unroll
            for (int tc = 0; tc < 8; ++tc)
                p = fmaf(silu_(acc[tm][tc][r] + bs2[tc]), f3v[tc], p);
            int row = w * 32 + tm * 16 + q * 4 + r;
            red[row * 17 + n] = p;
        }
    __syncthreads();
    if (t < 128) {
        float s = 0.f;
#pragma unroll
        for (int x = 0; x < 16; ++x) s += red[t * 17 + x];
        out[perm[row0 + t]] = sigm_(s + f3b[0]);
    }
}

// ---------- mfmm_te: t_e = e@Aw + Ab + Bh[psrc] + Ch[pdst] -> T, column stat partials
__global__ __launch_bounds__(256, 4) void mfmm_te_kernel(
    const unsigned short* __restrict__ A,   // e_bf (permuted order)
    const unsigned short* __restrict__ WT,
    const float* __restrict__ bias,
    const float* __restrict__ Bh, const float* __restrict__ Ch,
    const int* __restrict__ psrc, const int* __restrict__ pdst,
    unsigned short* __restrict__ T,
    float* __restrict__ P)
{
    __shared__ unsigned short sW[128 * SWT_STRIDE];
    const int t = threadIdx.x;
    const int w = t >> 6, lane = t & 63;
    const int q = lane >> 4, n = lane & 15;
    const int row0 = blockIdx.x * 128;

#pragma unroll
    for (int i = 0; i < 8; ++i) {
        int flat = t * 8 + i * 2048;
        int r = flat >> 7, k = flat & 127;
        *(s16x8*)&sW[r * SWT_STRIDE + k] = *(const s16x8*)(WT + flat);
    }
    __syncthreads();

    f32x4 acc[2][8];
#pragma unroll
    for (int tm = 0; tm < 2; ++tm)
#pragma unroll
        for (int tc = 0; tc < 8; ++tc) acc[tm][tc] = (f32x4){0.f, 0.f, 0.f, 0.f};

    const unsigned short* a0p = A + (size_t)(row0 + w * 32 + n) * D + q * 8;

#pragma unroll
    for (int kk = 0; kk < 128; kk += 32) {
        s16x8 af0 = *(const s16x8*)(a0p + kk);
        s16x8 af1 = *(const s16x8*)(a0p + 16 * D + kk);
#pragma unroll
        for (int tc = 0; tc < 8; ++tc) {
            s16x8 bf = *(const s16x8*)&sW[(tc * 16 + n) * SWT_STRIDE + kk + q * 8];
            acc[0][tc] = __builtin_amdgcn_mfma_f32_16x16x32_bf16(af0, bf, acc[0][tc], 0, 0, 0);
            acc[1][tc] = __builtin_amdgcn_mfma_f32_16x16x32_bf16(af1, bf, acc[1][tc], 0, 0, 0);
        }
    }

    float bs[8];
#pragma unroll
    for (int tc = 0; tc < 8; ++tc) bs[tc] = bias[tc * 16 + n];

    __syncthreads();
#pragma unroll
    for (int tm = 0; tm < 2; ++tm)
#pragma unroll
        for (int tc = 0; tc < 8; ++tc)
#pragma unroll
            for (int r = 0; r < 4; ++r) {
                int row = w * 32 + tm * 16 + q * 4 + r;
                int col = tc * 16 + n;
                sW[row * SWT_STRIDE + col] = f2bf(acc[tm][tc][r] + bs[tc]);
            }
    __syncthreads();

    const int c4 = (t & 31) * 4;
    const int rg = t >> 5;
    int srs[16], drs[16];
#pragma unroll
    for (int i = 0; i < 16; ++i) {
        int eid = row0 + rg + i * 8;
        srs[i] = psrc[eid];
        drs[i] = pdst[eid];
    }
    float s1[4] = {0.f, 0.f, 0.f, 0.f}, s2[4] = {0.f, 0.f, 0.f, 0.f};
#pragma unroll 4
    for (int i = 0; i < 16; ++i) {
        int row = rg + i * 8;
        int eid = row0 + row;
        float4 bv = *(const float4*)(Bh + (size_t)srs[i] * D + c4);
        float4 cv = *(const float4*)(Ch + (size_t)drs[i] * D + c4);
        ushort4 av = *(const ushort4*)&sW[row * SWT_STRIDE + c4];
        float t0 = bf2f(av.x) + bv.x + cv.x;
        float t1 = bf2f(av.y) + bv.y + cv.y;
        float t2 = bf2f(av.z) + bv.z + cv.z;
        float t3 = bf2f(av.w) + bv.w + cv.w;
        *(ushort4*)(T + (size_t)eid * D + c4) =
            make_ushort4(f2bf(t0), f2bf(t1), f2bf(t2), f2bf(t3));
        s1[0] += t0; s2[0] = fmaf(t0, t0, s2[0]);
        s1[1] += t1; s2[1] = fmaf(t1, t1, s2[1]);
        s1[2] += t2; s2[2] = fmaf(t2, t2, s2[2]);
        s1[3] += t3; s2[3] = fmaf(t3, t3, s2[3]);
    }
    __syncthreads();
    float* red = (float*)sW;
#pragma unroll
    for (int j = 0; j < 4; ++j) {
        red[rg * 128 + c4 + j] = s1[j];
        red[1024 + rg * 128 + c4 + j] = s2[j];
    }
    __syncthreads();
    if (t < 128) {
        float a = 0.f, b = 0.f;
#pragma unroll
        for (int g = 0; g < 8; ++g) { a += red[g * 128 + t]; b += red[1024 + g * 128 + t]; }
        P[(size_t)blockIdx.x * 256 + t] = a;
        P[(size_t)blockIdx.x * 256 + 128 + t] = b;
    }
}

// ---------- fused gather agg + apply_e (no atomics; all 3 layers; independent waves)
__global__ __launch_bounds__(256) void agg_apply_kernel(
    unsigned short* E, const unsigned short* __restrict__ T,
    const float* __restrict__ Vh, const float* __restrict__ stats,
    const int* __restrict__ rowptr, const int* __restrict__ pdst,
    const float* __restrict__ inv_cnt, float* __restrict__ Uh)
{
    int n = blockIdx.x * 4 + (threadIdx.x >> 6);
    if (n >= NN) return;
    int lane = threadIdx.x & 63;
    int c2 = lane * 2;
    float2 sc = *(const float2*)(stats + 2 * D + c2);
    float2 sh = *(const float2*)(stats + 3 * D + c2);
    int beg = rowptr[n], end = rowptr[n + 1];
    float a0 = 0.f, a1 = 0.f;
    for (int j = beg; j < end; ++j) {
        int g = pdst[j];
        unsigned int ep = *(const unsigned int*)(E + (size_t)j * D + c2);
        float2 vv = *(const float2*)(Vh + (size_t)g * D + c2);
        float e0 = bf2f((unsigned short)(ep & 0xffff));
        float e1 = bf2f((unsigned short)(ep >> 16));
        a0 = fmaf(sigm_(e0), vv.x, a0);
        a1 = fmaf(sigm_(e1), vv.y, a1);
        unsigned int tp = *(const unsigned int*)(T + (size_t)j * D + c2);
        float t0 = bf2f((unsigned short)(tp & 0xffff));
        float t1 = bf2f((unsigned short)(tp >> 16));
        unsigned short o0 = f2bf(e0 + silu_(fmaf(t0, sc.x, sh.x)));
        unsigned short o1 = f2bf(e1 + silu_(fmaf(t1, sc.y, sh.y)));
        *(unsigned int*)(E + (size_t)j * D + c2) = ((unsigned int)o1 << 16) | o0;
    }
    float ic = inv_cnt[n];
    size_t o = (size_t)n * D + c2;
    float2 u = *(const float2*)(Uh + o);
    u.x = fmaf(a0, ic, u.x);
    u.y = fmaf(a1, ic, u.y);
    *(float2*)(Uh + o) = u;
}

// ---------- stats: partial reduce (no atomics) + merged finalize
__global__ __launch_bounds__(256) void reduceE_kernel(
    const float* __restrict__ P, int nblk, float* __restrict__ P2)
{
    int t = threadIdx.x;
    float s = 0.f;
    for (int j = blockIdx.x; j < nblk; j += gridDim.x)
        s += P[(size_t)j * 256 + t];
    P2[blockIdx.x * 256 + t] = s;
}

__global__ void finalize2_kernel(const float* __restrict__ P, int nblk,
                                 const float* __restrict__ gamma,
                                 const float* __restrict__ beta,
                                 float inv_rows, float* __restrict__ stats)
{
    int c = threadIdx.x;  // 128
    float s1 = 0.f, s2 = 0.f;
    for (int j = 0; j < nblk; ++j) {
        s1 += P[j * 256 + c];
        s2 += P[j * 256 + 128 + c];
    }
    float m = s1 * inv_rows;
    float v = s2 * inv_rows - m * m;
    float rstd = rsqrtf(v + BN_EPS);
    float sc = gamma[c] * rstd;
    stats[2 * D + c] = sc;
    stats[3 * D + c] = beta[c] - m * sc;
}

// ---------- input projections (init_h emits hi/lo too)
__global__ __launch_bounds__(256) void init_h_kernel(
    const float* __restrict__ x, const float* __restrict__ hp_w,
    const float* __restrict__ hp_b, float* __restrict__ h,
    unsigned short* __restrict__ hhi, unsigned short* __restrict__ hlo)
{
    int idx = blockIdx.x * 256 + threadIdx.x;
    int n = idx >> 5, d = (idx & 31) * 4;
    if (n >= NN) return;
    float x0 = x[n * 2], x1 = x[n * 2 + 1];
    float4 w0 = *(const float4*)(hp_w + d);
    float4 w1 = *(const float4*)(hp_w + D + d);
    float4 b = *(const float4*)(hp_b + d);
    float4 o;
    o.x = silu_(fmaf(x0, w0.x, fmaf(x1, w1.x, b.x)));
    o.y = silu_(fmaf(x0, w0.y, fmaf(x1, w1.y, b.y)));
    o.z = silu_(fmaf(x0, w0.z, fmaf(x1, w1.z, b.z)));
    o.w = silu_(fmaf(x0, w0.w, fmaf(x1, w1.w, b.w)));
    *(float4*)(h + (size_t)n * D + d) = o;
    ushort4 hi = make_ushort4(f2bf(o.x), f2bf(o.y), f2bf(o.z), f2bf(o.w));
    ushort4 lo = make_ushort4(f2bf(o.x - bf2f(hi.x)), f2bf(o.y - bf2f(hi.y)),
                              f2bf(o.z - bf2f(hi.z)), f2bf(o.w - bf2f(hi.w)));
    *(ushort4*)(hhi + (size_t)n * D + d) = hi;
    *(ushort4*)(hlo + (size_t)n * D + d) = lo;
}

// init_e in PERMUTED order: row j <- edge eidx[j]
__global__ __launch_bounds__(256) void init_e_kernel(
    const float* __restrict__ ea, const int* __restrict__ eidx,
    const float* __restrict__ ep_w, const float* __restrict__ ep_b,
    unsigned short* __restrict__ e)
{
    int idx = blockIdx.x * 256 + threadIdx.x;
    int j = idx >> 5, d = (idx & 31) * 4;
    if (j >= NE) return;
    float a = ea[eidx[j]];
    float4 w = *(const float4*)(ep_w + d);
    float4 b = *(const float4*)(ep_b + d);
    ushort4 o;
    o.x = f2bf(silu_(fmaf(a, w.x, b.x)));
    o.y = f2bf(silu_(fmaf(a, w.y, b.y)));
    o.z = f2bf(silu_(fmaf(a, w.z, b.z)));
    o.w = f2bf(silu_(fmaf(a, w.w, b.w)));
    *(ushort4*)(e + (size_t)j * D + d) = o;
}

// ---------- CSR build
__global__ __launch_bounds__(256) void deg_kernel(const int* __restrict__ src, int* __restrict__ deg)
{
    int i = blockIdx.x * 256 + threadIdx.x;
    if (i < NE) atomicAdd(&deg[src[i]], 1);
}

__global__ __launch_bounds__(256) void scan_kernel(
    const int* __restrict__ deg, int* __restrict__ rowptr, float* __restrict__ inv_cnt)
{
    __shared__ int chunk[256];
    const int t = threadIdx.x;
    const int CH = (NN + 255) / 256;
    int s = 0;
    for (int i = 0; i < CH; ++i) {
        int idx = t * CH + i;
        if (idx < NN) s += deg[idx];
    }
    chunk[t] = s;
    __syncthreads();
    for (int offs = 1; offs < 256; offs <<= 1) {
        int v = (t >= offs) ? chunk[t - offs] : 0;
        __syncthreads();
        chunk[t] += v;
        __syncthreads();
    }
    int base = (t == 0) ? 0 : chunk[t - 1];
    for (int i = 0; i < CH; ++i) {
        int idx = t * CH + i;
        if (idx < NN) {
            rowptr[idx] = base;
            int d = deg[idx];
            inv_cnt[idx] = 1.0f / fmaxf((float)d, 1.0f);
            base += d;
        }
    }
    if (t == 255) rowptr[NN] = base;
}

__global__ __launch_bounds__(256) void fill_kernel(
    const int* __restrict__ src, const int* __restrict__ dst,
    const int* __restrict__ rowptr, int* __restrict__ cursor,
    int* __restrict__ eidx, int* __restrict__ psrc, int* __restrict__ pdst)
{
    int i = blockIdx.x * 256 + threadIdx.x;
    if (i >= NE) return;
    int s = src[i];
    int p = atomicAdd(&cursor[s], 1);
    int pos = rowptr[s] + p;
    eidx[pos] = i;
    psrc[pos] = s;
    pdst[pos] = dst[i];
}

// column stats partials of fp32 t_h (exactly 20 blocks; no atomics)
__global__ __launch_bounds__(256) void colstats_h_kernel(
    const float* __restrict__ Th, float* __restrict__ PH)
{
    __shared__ float red1[8][128], red2[8][128];
    int t = threadIdx.x;
    int c0 = (t & 31) * 4, half = t >> 5;
    int rbase = blockIdx.x * 1024;
    float s1[4] = {0, 0, 0, 0}, s2[4] = {0, 0, 0, 0};
    for (int i = 0; i < 128; ++i) {
        int r = rbase + half + 8 * i;
        if (r >= NN) break;
        float4 v = *(const float4*)(Th + (size_t)r * D + c0);
        s1[0] += v.x; s2[0] = fmaf(v.x, v.x, s2[0]);
        s1[1] += v.y; s2[1] = fmaf(v.y, v.y, s2[1]);
        s1[2] += v.z; s2[2] = fmaf(v.z, v.z, s2[2]);
        s1[3] += v.w; s2[3] = fmaf(v.w, v.w, s2[3]);
    }
#pragma unroll
    for (int j = 0; j < 4; ++j) { red1[half][c0 + j] = s1[j]; red2[half][c0 + j] = s2[j]; }
    __syncthreads();
    if (t < 128) {
        float a = 0.f, b = 0.f;
#pragma unroll
        for (int hh = 0; hh < 8; ++hh) { a += red1[hh][t]; b += red2[hh][t]; }
        PH[(size_t)blockIdx.x * 256 + t] = a;
        PH[(size_t)blockIdx.x * 256 + 128 + t] = b;
    }
}

// h += silu(t_h*sc+sh); also emit h_hi/h_lo for next layer's node matmul
__global__ __launch_bounds__(256) void apply_h_kernel(
    float* __restrict__ h, const float* __restrict__ Th, const float* __restrict__ stats,
    unsigned short* __restrict__ hhi, unsigned short* __restrict__ hlo)
{
    int idx = blockIdx.x * 256 + threadIdx.x;
    int r = idx >> 5, d = (idx & 31) * 4;
    if (r >= NN) return;
    float4 tv = *(const float4*)(Th + (size_t)r * D + d);
    float4 sc = *(const float4*)(stats + 2 * D + d);
    float4 sh = *(const float4*)(stats + 3 * D + d);
    float4 hv = *(const float4*)(h + (size_t)r * D + d);
    hv.x += silu_(fmaf(tv.x, sc.x, sh.x));
    hv.y += silu_(fmaf(tv.y, sc.y, sh.y));
    hv.z += silu_(fmaf(tv.z, sc.z, sh.z));
    hv.w += silu_(fmaf(tv.w, sc.w, sh.w));
    *(float4*)(h + (size_t)r * D + d) = hv;
    ushort4 hi = make_ushort4(f2bf(hv.x), f2bf(hv.y), f2bf(hv.z), f2bf(hv.w));
    ushort4 lo = make_ushort4(f2bf(hv.x - bf2f(hi.x)), f2bf(hv.y - bf2f(hi.y)),
                              f2bf(hv.z - bf2f(hi.z)), f2bf(hv.w - bf2f(hi.w)));
    *(ushort4*)(hhi + (size_t)r * D + d) = hi;
    *(ushort4*)(hlo + (size_t)r * D + d) = lo;
}

extern "C" void kernel_launch(void* const* d_in, const int* in_sizes, int n_in,
                              void* d_out, int out_size, void* d_ws, size_t ws_size,
                              hipStream_t stream)
{
    (void)in_sizes; (void)n_in; (void)out_size;
    const float* x = (const float*)d_in[0];
    const float* edge_attr = (const float*)d_in[1];
    const int* edge_index = (const int*)d_in[2];
    const int* src = edge_index;
    const int* dst = edge_index + NE;
    const float* hp_w = (const float*)d_in[3];
    const float* hp_b = (const float*)d_in[4];
    const float* ep_w = (const float*)d_in[5];
    const float* ep_b = (const float*)d_in[6];
    const float* Uw = (const float*)d_in[7];
    const float* Ub = (const float*)d_in[8];
    const float* Vw = (const float*)d_in[9];
    const float* Vb = (const float*)d_in[10];
    const float* Aw = (const float*)d_in[11];
    const float* Ab = (const float*)d_in[12];
    const float* Bw = (const float*)d_in[13];
    const float* Bb = (const float*)d_in[14];
    const float* Cw = (const float*)d_in[15];
    const float* Cb = (const float*)d_in[16];
    const float* h_gamma = (const float*)d_in[17];
    const float* h_beta = (const float*)d_in[18];
    const float* e_gamma = (const float*)d_in[19];
    const float* e_beta = (const float*)d_in[20];
    const float* f1w = (const float*)d_in[21];
    const float* f1b = (const float*)d_in[22];
    const float* f2w = (const float*)d_in[23];
    const float* f2b = (const float*)d_in[24];
    const float* f3w = (const float*)d_in[25];
    const float* f3b = (const float*)d_in[26];
    float* out = (float*)d_out;

    size_t off = 0;
    auto alloc = [&](size_t nbytes) {
        void* p = (char*)d_ws + off;
        off += ((nbytes + 255) / 256) * 256;
        return p;
    };
    unsigned short* e_bf = (unsigned short*)alloc((size_t)NE * D * 2);
    unsigned short* t_bf = (unsigned short*)alloc((size_t)NE * D * 2);
    float* h  = (float*)alloc((size_t)NN * D * 4);
    unsigned short* h_hi = (unsigned short*)alloc((size_t)NN * D * 2);
    unsigned short* h_lo = (unsigned short*)alloc((size_t)NN * D * 2);
    float* Uh = (float*)alloc((size_t)NN * D * 4);
    float* Vh = (float*)alloc((size_t)NN * D * 4);
    float* Bh = (float*)alloc((size_t)NN * D * 4);
    float* Ch = (float*)alloc((size_t)NN * D * 4);
    int* deg = (int*)alloc(NN * 4);
    int* rowptr = (int*)alloc((NN + 1) * 4);
    int* cursor = (int*)alloc(NN * 4);
    int* eidx = (int*)alloc((size_t)NE * 4);
    int* psrc = (int*)alloc((size_t)NE * 4);
    int* pdst = (int*)alloc((size_t)NE * 4);
    float* inv_cnt = (float*)alloc(NN * 4);
    float* statsH = (float*)alloc(4 * D * 4);
    float* statsE = (float*)alloc(4 * D * 4);
    float* Pstats = (float*)alloc((size_t)(NE / 128) * 256 * 4);
    float* PstatsH = (float*)alloc(20 * 256 * 4);
    float* PE2 = (float*)alloc(10 * 256 * 4);
    unsigned short* wtsNhi = (unsigned short*)alloc((size_t)12 * D * D * 2);
    unsigned short* wtsNlo = (unsigned short*)alloc((size_t)12 * D * D * 2);
    unsigned short* wtsE = (unsigned short*)alloc((size_t)5 * D * D * 2);  // A0,A1,A2,F1,F2

    if (off > ws_size) return;  // diagnostic guard

    const int nodeBlocks32 = (NN * 32 + 255) / 256;  // 2500
    const int edgeBlocks32 = (NE * 32) / 256;        // 40000
    const int nodeTiles = (NN + 127) / 128;          // 157
    const int edgeTiles = NE / 128;                  // 2500
    const int hBlocks = (NN + 1023) / 1024;          // 20

    // CSR build (needed before permuted init_e)
    hipMemsetAsync(deg, 0, NN * sizeof(int), stream);
    hipMemsetAsync(cursor, 0, NN * sizeof(int), stream);
    deg_kernel<<<NE / 256, 256, 0, stream>>>(src, deg);
    scan_kernel<<<1, 256, 0, stream>>>(deg, rowptr, inv_cnt);
    fill_kernel<<<NE / 256, 256, 0, stream>>>(src, dst, rowptr, cursor, eidx, psrc, pdst);

    init_h_kernel<<<nodeBlocks32, 256, 0, stream>>>(x, hp_w, hp_b, h, h_hi, h_lo);
    init_e_kernel<<<edgeBlocks32, 256, 0, stream>>>(edge_attr, eidx, ep_w, ep_b, e_bf);

    // all 17 weight conversions in one dispatch
    ConvJobs cj;
    const float* nodeW[4][3] = {{Uw, Uw + 16384, Uw + 32768},
                                {Vw, Vw + 16384, Vw + 32768},
                                {Bw, Bw + 16384, Bw + 32768},
                                {Cw, Cw + 16384, Cw + 32768}};
    for (int l = 0; l < LAYERS; ++l)
        for (int j = 0; j < 4; ++j) {
            int slot = l * 4 + j;
            cj.W[slot] = nodeW[j][l];
            cj.Hi[slot] = wtsNhi + (size_t)slot * D * D;
            cj.Lo[slot] = wtsNlo + (size_t)slot * D * D;
        }
    const float* edgeW[5] = {Aw, Aw + 16384, Aw + 32768, f1w, f2w};
    for (int j = 0; j < 5; ++j) {
        cj.W[12 + j] = edgeW[j];
        cj.Hi[12 + j] = wtsE + (size_t)j * D * D;
        cj.Lo[12 + j] = nullptr;
    }
    conv_all_kernel<<<dim3(64, 17), 256, 0, stream>>>(cj);

    for (int l = 0; l < LAYERS; ++l) {
        const size_t bl = (size_t)l * D;

        MatsB2 m4;
        for (int j = 0; j < 4; ++j) {
            size_t slot = (size_t)(l * 4 + j) * D * D;
            m4.WThi[j] = wtsNhi + slot;
            m4.WTlo[j] = wtsNlo + slot;
        }
        m4.b[0] = Ub + bl; m4.b[1] = Vb + bl; m4.b[2] = Bb + bl; m4.b[3] = Cb + bl;
        m4.C[0] = Uh; m4.C[1] = Vh; m4.C[2] = Bh; m4.C[3] = Ch;
        mfmm_node_kernel<<<dim3(nodeTiles, 4), 256, 0, stream>>>(h_hi, h_lo, NN, m4);

        // t_e matmul + gathers + stat partials
        mfmm_te_kernel<<<edgeTiles, 256, 0, stream>>>(
            e_bf, wtsE + (size_t)l * D * D, Ab + bl, Bh, Ch, psrc, pdst, t_bf, Pstats);

        // e stats
        reduceE_kernel<<<10, 256, 0, stream>>>(Pstats, edgeTiles, PE2);
        finalize2_kernel<<<1, D, 0, stream>>>(PE2, 10, e_gamma + bl, e_beta + bl,
                                              1.0f / NE, statsE);

        // fused aggregation + e-update (all layers; e_bf fully updated after layer 2)
        agg_apply_kernel<<<(NN + 3) / 4, 256, 0, stream>>>(
            e_bf, t_bf, Vh, statsE, rowptr, pdst, inv_cnt, Uh);

        // h update (partials -> merged finalize)
        colstats_h_kernel<<<hBlocks, 256, 0, stream>>>(Uh, PstatsH);
        finalize2_kernel<<<1, D, 0, stream>>>(PstatsH, hBlocks, h_gamma + bl, h_beta + bl,
                                              1.0f / NN, statsH);
        apply_h_kernel<<<nodeBlocks32, 256, 0, stream>>>(h, Uh, statsH, h_hi, h_lo);
    }

    // fused final MLP: f1 + f2 + f3 (e_bf already holds final e state)
    mfmm_final_kernel<<<edgeTiles, 256, 0, stream>>>(
        e_bf,
        wtsE + (size_t)3 * D * D, f1b,
        wtsE + (size_t)4 * D * D, f2b,
        f3w, f3b, out, eidx);
}

// Round 18
// 969.800 us; speedup vs baseline: 1.2256x; 1.0980x over previous
//
#include <hip/hip_runtime.h>

#define NN 20000
#define NE 320000
#define D 128
#define LAYERS 3
#define BN_EPS 1e-5f

typedef __attribute__((ext_vector_type(8))) short s16x8;
typedef __attribute__((ext_vector_type(4))) float f32x4;

__device__ __forceinline__ float sigm_(float x) { return 1.0f / (1.0f + __expf(-x)); }
__device__ __forceinline__ float silu_(float x) { return x * sigm_(x); }
__device__ __forceinline__ float bf2f(unsigned short u) {
    union { unsigned int u; float f; } v; v.u = ((unsigned int)u) << 16; return v.f;
}
__device__ __forceinline__ unsigned short f2bf(float f) {
    union { float f; unsigned int u; } v; v.f = f;
    return (unsigned short)((v.u + 0x7FFFu + ((v.u >> 16) & 1u)) >> 16);
}

#define SWT_STRIDE 136

// ---------- all weight conversions in one dispatch: blockIdx.y = job
struct ConvJobs {
    const float* W[17];
    unsigned short* Hi[17];
    unsigned short* Lo[17];  // nullptr => single bf16 convert
};
__global__ __launch_bounds__(256) void conv_all_kernel(ConvJobs jobs)
{
    int y = blockIdx.y;
    int idx = blockIdx.x * 256 + threadIdx.x;  // 16384
    int k = idx >> 7, n = idx & 127;
    float v = jobs.W[y][idx];
    unsigned short hi = f2bf(v);
    jobs.Hi[y][n * 128 + k] = hi;
    if (jobs.Lo[y]) jobs.Lo[y][n * 128 + k] = f2bf(v - bf2f(hi));
}

struct MatsB2 {
    const unsigned short* WThi[4];
    const unsigned short* WTlo[4];
    const float* b[4];
    float* C[4];
};

// ---------- split-precision MFMA node matmul
__global__ __launch_bounds__(256, 2) void mfmm_node_kernel(
    const unsigned short* __restrict__ Ahi, const unsigned short* __restrict__ Alo,
    int M, MatsB2 ms)
{
    __shared__ unsigned short sW[128 * SWT_STRIDE];
    const int mat = blockIdx.y;
    const unsigned short* __restrict__ WThi = ms.WThi[mat];
    const unsigned short* __restrict__ WTlo = ms.WTlo[mat];
    const float* __restrict__ bias = ms.b[mat];
    float* __restrict__ C = ms.C[mat];
    const int t = threadIdx.x;
    const int w = t >> 6, lane = t & 63;
    const int q = lane >> 4, n = lane & 15;
    const int row0 = blockIdx.x * 128;

    int r0 = row0 + w * 32 + n;      if (r0 >= M) r0 = M - 1;
    int r1 = row0 + w * 32 + 16 + n; if (r1 >= M) r1 = M - 1;
    const size_t o0 = (size_t)r0 * D + q * 8;
    const size_t o1 = (size_t)r1 * D + q * 8;

    s16x8 ah[2][4], al[2][4];
#pragma unroll
    for (int kk = 0; kk < 4; ++kk) {
        ah[0][kk] = *(const s16x8*)(Ahi + o0 + kk * 32);
        ah[1][kk] = *(const s16x8*)(Ahi + o1 + kk * 32);
        al[0][kk] = *(const s16x8*)(Alo + o0 + kk * 32);
        al[1][kk] = *(const s16x8*)(Alo + o1 + kk * 32);
    }

    f32x4 acc[2][8];
#pragma unroll
    for (int tm = 0; tm < 2; ++tm)
#pragma unroll
        for (int tc = 0; tc < 8; ++tc) acc[tm][tc] = (f32x4){0.f, 0.f, 0.f, 0.f};

    // pass 1: W_hi (a_hi + a_lo)
#pragma unroll
    for (int i = 0; i < 8; ++i) {
        int flat = t * 8 + i * 2048;
        int r = flat >> 7, k = flat & 127;
        *(s16x8*)&sW[r * SWT_STRIDE + k] = *(const s16x8*)(WThi + flat);
    }
    __syncthreads();
#pragma unroll
    for (int kk = 0; kk < 4; ++kk) {
#pragma unroll
        for (int tc = 0; tc < 8; ++tc) {
            s16x8 bf = *(const s16x8*)&sW[(tc * 16 + n) * SWT_STRIDE + kk * 32 + q * 8];
            acc[0][tc] = __builtin_amdgcn_mfma_f32_16x16x32_bf16(ah[0][kk], bf, acc[0][tc], 0, 0, 0);
            acc[1][tc] = __builtin_amdgcn_mfma_f32_16x16x32_bf16(ah[1][kk], bf, acc[1][tc], 0, 0, 0);
            acc[0][tc] = __builtin_amdgcn_mfma_f32_16x16x32_bf16(al[0][kk], bf, acc[0][tc], 0, 0, 0);
            acc[1][tc] = __builtin_amdgcn_mfma_f32_16x16x32_bf16(al[1][kk], bf, acc[1][tc], 0, 0, 0);
        }
    }
    __syncthreads();

    // pass 2: W_lo (a_hi only)
#pragma unroll
    for (int i = 0; i < 8; ++i) {
        int flat = t * 8 + i * 2048;
        int r = flat >> 7, k = flat & 127;
        *(s16x8*)&sW[r * SWT_STRIDE + k] = *(const s16x8*)(WTlo + flat);
    }
    __syncthreads();
#pragma unroll
    for (int kk = 0; kk < 4; ++kk) {
#pragma unroll
        for (int tc = 0; tc < 8; ++tc) {
            s16x8 bf = *(const s16x8*)&sW[(tc * 16 + n) * SWT_STRIDE + kk * 32 + q * 8];
            acc[0][tc] = __builtin_amdgcn_mfma_f32_16x16x32_bf16(ah[0][kk], bf, acc[0][tc], 0, 0, 0);
            acc[1][tc] = __builtin_amdgcn_mfma_f32_16x16x32_bf16(ah[1][kk], bf, acc[1][tc], 0, 0, 0);
        }
    }

    float bs[8];
#pragma unroll
    for (int tc = 0; tc < 8; ++tc) bs[tc] = bias[tc * 16 + n];

#pragma unroll
    for (int tm = 0; tm < 2; ++tm)
#pragma unroll
        for (int r = 0; r < 4; ++r) {
            int row = row0 + w * 32 + tm * 16 + q * 4 + r;
            if (row >= M) continue;
#pragma unroll
            for (int tc = 0; tc < 8; ++tc)
                C[(size_t)row * D + tc * 16 + n] = acc[tm][tc][r] + bs[tc];
        }
}

// ---------- fused final MLP (dual LDS, 2 blocks/CU, e pre-updated by agg_apply)
__global__ __launch_bounds__(256, 2) void mfmm_final_kernel(
    const unsigned short* __restrict__ E,
    const unsigned short* __restrict__ WT1, const float* __restrict__ b1,
    const unsigned short* __restrict__ WT2, const float* __restrict__ b2,
    const float* __restrict__ f3w, const float* __restrict__ f3b,
    float* __restrict__ out, const int* __restrict__ perm)
{
    __shared__ unsigned short sW1[128 * SWT_STRIDE];
    __shared__ unsigned short sW2[128 * SWT_STRIDE];
    const int t = threadIdx.x;
    const int w = t >> 6, lane = t & 63;
    const int q = lane >> 4, n = lane & 15;
    const int row0 = blockIdx.x * 128;

#pragma unroll
    for (int i = 0; i < 8; ++i) {
        int flat = t * 8 + i * 2048;
        int r = flat >> 7, k = flat & 127;
        *(s16x8*)&sW1[r * SWT_STRIDE + k] = *(const s16x8*)(WT1 + flat);
    }
    __syncthreads();

    f32x4 acc[2][8];
#pragma unroll
    for (int tm = 0; tm < 2; ++tm)
#pragma unroll
        for (int tc = 0; tc < 8; ++tc) acc[tm][tc] = (f32x4){0.f, 0.f, 0.f, 0.f};

    const unsigned short* a0p = E + (size_t)(row0 + w * 32 + n) * D + q * 8;

#pragma unroll
    for (int kk = 0; kk < 128; kk += 32) {
        s16x8 af0 = *(const s16x8*)(a0p + kk);
        s16x8 af1 = *(const s16x8*)(a0p + 16 * D + kk);
#pragma unroll
        for (int tc = 0; tc < 8; ++tc) {
            s16x8 bf = *(const s16x8*)&sW1[(tc * 16 + n) * SWT_STRIDE + kk + q * 8];
            acc[0][tc] = __builtin_amdgcn_mfma_f32_16x16x32_bf16(af0, bf, acc[0][tc], 0, 0, 0);
            acc[1][tc] = __builtin_amdgcn_mfma_f32_16x16x32_bf16(af1, bf, acc[1][tc], 0, 0, 0);
        }
    }

    float bs1[8];
#pragma unroll
    for (int tc = 0; tc < 8; ++tc) bs1[tc] = b1[tc * 16 + n];
#pragma unroll
    for (int tm = 0; tm < 2; ++tm)
#pragma unroll
        for (int tc = 0; tc < 8; ++tc)
#pragma unroll
            for (int r = 0; r < 4; ++r) {
                int row = w * 32 + tm * 16 + q * 4 + r;
                int col = tc * 16 + n;
                sW2[row * SWT_STRIDE + col] = f2bf(silu_(acc[tm][tc][r] + bs1[tc]));
            }
    __syncthreads();

#pragma unroll
    for (int i = 0; i < 8; ++i) {
        int flat = t * 8 + i * 2048;
        int r = flat >> 7, k = flat & 127;
        *(s16x8*)&sW1[r * SWT_STRIDE + k] = *(const s16x8*)(WT2 + flat);
    }
    __syncthreads();

#pragma unroll
    for (int tm = 0; tm < 2; ++tm)
#pragma unroll
        for (int tc = 0; tc < 8; ++tc) acc[tm][tc] = (f32x4){0.f, 0.f, 0.f, 0.f};
#pragma unroll
    for (int kk = 0; kk < 128; kk += 32) {
        s16x8 af0 = *(const s16x8*)&sW2[(w * 32 + n) * SWT_STRIDE + kk + q * 8];
        s16x8 af1 = *(const s16x8*)&sW2[(w * 32 + 16 + n) * SWT_STRIDE + kk + q * 8];
#pragma unroll
        for (int tc = 0; tc < 8; ++tc) {
            s16x8 bf = *(const s16x8*)&sW1[(tc * 16 + n) * SWT_STRIDE + kk + q * 8];
            acc[0][tc] = __builtin_amdgcn_mfma_f32_16x16x32_bf16(af0, bf, acc[0][tc], 0, 0, 0);
            acc[1][tc] = __builtin_amdgcn_mfma_f32_16x16x32_bf16(af1, bf, acc[1][tc], 0, 0, 0);
        }
    }

    float bs2[8], f3v[8];
#pragma unroll
    for (int tc = 0; tc < 8; ++tc) {
        bs2[tc] = b2[tc * 16 + n];
        f3v[tc] = f3w[tc * 16 + n];
    }
    __syncthreads();
    float* red = (float*)sW2;  // [128][17]
#pragma unroll
    for (int tm = 0; tm < 2; ++tm)
#pragma unroll
        for (int r = 0; r < 4; ++r) {
            float p = 0.f;
#pragma unroll
            for (int tc = 0; tc < 8; ++tc)
                p = fmaf(silu_(acc[tm][tc][r] + bs2[tc]), f3v[tc], p);
            int row = w * 32 + tm * 16 + q * 4 + r;
            red[row * 17 + n] = p;
        }
    __syncthreads();
    if (t < 128) {
        float s = 0.f;
#pragma unroll
        for (int x = 0; x < 16; ++x) s += red[t * 17 + x];
        out[perm[row0 + t]] = sigm_(s + f3b[0]);
    }
}

// ---------- mfmm_te: t_e = e@Aw + Ab + Bh[psrc] + Ch[pdst] -> T, column stat partials
__global__ __launch_bounds__(256, 4) void mfmm_te_kernel(
    const unsigned short* __restrict__ A,   // e_bf (permuted order)
    const unsigned short* __restrict__ WT,
    const float* __restrict__ bias,
    const float* __restrict__ Bh, const float* __restrict__ Ch,
    const int* __restrict__ psrc, const int* __restrict__ pdst,
    unsigned short* __restrict__ T,
    float* __restrict__ P)
{
    __shared__ unsigned short sW[128 * SWT_STRIDE];
    const int t = threadIdx.x;
    const int w = t >> 6, lane = t & 63;
    const int q = lane >> 4, n = lane & 15;
    const int row0 = blockIdx.x * 128;

#pragma unroll
    for (int i = 0; i < 8; ++i) {
        int flat = t * 8 + i * 2048;
        int r = flat >> 7, k = flat & 127;
        *(s16x8*)&sW[r * SWT_STRIDE + k] = *(const s16x8*)(WT + flat);
    }
    __syncthreads();

    f32x4 acc[2][8];
#pragma unroll
    for (int tm = 0; tm < 2; ++tm)
#pragma unroll
        for (int tc = 0; tc < 8; ++tc) acc[tm][tc] = (f32x4){0.f, 0.f, 0.f, 0.f};

    const unsigned short* a0p = A + (size_t)(row0 + w * 32 + n) * D + q * 8;

#pragma unroll
    for (int kk = 0; kk < 128; kk += 32) {
        s16x8 af0 = *(const s16x8*)(a0p + kk);
        s16x8 af1 = *(const s16x8*)(a0p + 16 * D + kk);
#pragma unroll
        for (int tc = 0; tc < 8; ++tc) {
            s16x8 bf = *(const s16x8*)&sW[(tc * 16 + n) * SWT_STRIDE + kk + q * 8];
            acc[0][tc] = __builtin_amdgcn_mfma_f32_16x16x32_bf16(af0, bf, acc[0][tc], 0, 0, 0);
            acc[1][tc] = __builtin_amdgcn_mfma_f32_16x16x32_bf16(af1, bf, acc[1][tc], 0, 0, 0);
        }
    }

    float bs[8];
#pragma unroll
    for (int tc = 0; tc < 8; ++tc) bs[tc] = bias[tc * 16 + n];

    __syncthreads();
#pragma unroll
    for (int tm = 0; tm < 2; ++tm)
#pragma unroll
        for (int tc = 0; tc < 8; ++tc)
#pragma unroll
            for (int r = 0; r < 4; ++r) {
                int row = w * 32 + tm * 16 + q * 4 + r;
                int col = tc * 16 + n;
                sW[row * SWT_STRIDE + col] = f2bf(acc[tm][tc][r] + bs[tc]);
            }
    __syncthreads();

    const int c4 = (t & 31) * 4;
    const int rg = t >> 5;
    int srs[16], drs[16];
#pragma unroll
    for (int i = 0; i < 16; ++i) {
        int eid = row0 + rg + i * 8;
        srs[i] = psrc[eid];
        drs[i] = pdst[eid];
    }
    float s1[4] = {0.f, 0.f, 0.f, 0.f}, s2[4] = {0.f, 0.f, 0.f, 0.f};
#pragma unroll 4
    for (int i = 0; i < 16; ++i) {
        int row = rg + i * 8;
        int eid = row0 + row;
        float4 bv = *(const float4*)(Bh + (size_t)srs[i] * D + c4);
        float4 cv = *(const float4*)(Ch + (size_t)drs[i] * D + c4);
        ushort4 av = *(const ushort4*)&sW[row * SWT_STRIDE + c4];
        float t0 = bf2f(av.x) + bv.x + cv.x;
        float t1 = bf2f(av.y) + bv.y + cv.y;
        float t2 = bf2f(av.z) + bv.z + cv.z;
        float t3 = bf2f(av.w) + bv.w + cv.w;
        *(ushort4*)(T + (size_t)eid * D + c4) =
            make_ushort4(f2bf(t0), f2bf(t1), f2bf(t2), f2bf(t3));
        s1[0] += t0; s2[0] = fmaf(t0, t0, s2[0]);
        s1[1] += t1; s2[1] = fmaf(t1, t1, s2[1]);
        s1[2] += t2; s2[2] = fmaf(t2, t2, s2[2]);
        s1[3] += t3; s2[3] = fmaf(t3, t3, s2[3]);
    }
    __syncthreads();
    float* red = (float*)sW;
#pragma unroll
    for (int j = 0; j < 4; ++j) {
        red[rg * 128 + c4 + j] = s1[j];
        red[1024 + rg * 128 + c4 + j] = s2[j];
    }
    __syncthreads();
    if (t < 128) {
        float a = 0.f, b = 0.f;
#pragma unroll
        for (int g = 0; g < 8; ++g) { a += red[g * 128 + t]; b += red[1024 + g * 128 + t]; }
        P[(size_t)blockIdx.x * 256 + t] = a;
        P[(size_t)blockIdx.x * 256 + 128 + t] = b;
    }
}

// ---------- fused gather agg + apply_e (no atomics; independent waves; 1-deep pipeline)
__global__ __launch_bounds__(256) void agg_apply_kernel(
    unsigned short* E, const unsigned short* __restrict__ T,
    const float* __restrict__ Vh, const float* __restrict__ stats,
    const int* __restrict__ rowptr, const int* __restrict__ pdst,
    const float* __restrict__ inv_cnt, float* __restrict__ Uh)
{
    int n = blockIdx.x * 4 + (threadIdx.x >> 6);
    if (n >= NN) return;
    int lane = threadIdx.x & 63;
    int c2 = lane * 2;
    float2 sc = *(const float2*)(stats + 2 * D + c2);
    float2 sh = *(const float2*)(stats + 3 * D + c2);
    int beg = rowptr[n], end = rowptr[n + 1];
    float a0 = 0.f, a1 = 0.f;

    if (beg < end) {
        int g = pdst[beg];
        unsigned int ep = *(const unsigned int*)(E + (size_t)beg * D + c2);
        unsigned int tp = *(const unsigned int*)(T + (size_t)beg * D + c2);
        for (int j = beg; j < end; ++j) {
            int jn = j + 1;
            int g2 = 0; unsigned int ep2 = 0, tp2 = 0;
            if (jn < end) {  // prefetch next iteration's inputs before consuming Vh[g]
                g2 = pdst[jn];
                ep2 = *(const unsigned int*)(E + (size_t)jn * D + c2);
                tp2 = *(const unsigned int*)(T + (size_t)jn * D + c2);
            }
            float2 vv = *(const float2*)(Vh + (size_t)g * D + c2);
            float e0 = bf2f((unsigned short)(ep & 0xffff));
            float e1 = bf2f((unsigned short)(ep >> 16));
            a0 = fmaf(sigm_(e0), vv.x, a0);
            a1 = fmaf(sigm_(e1), vv.y, a1);
            float t0 = bf2f((unsigned short)(tp & 0xffff));
            float t1 = bf2f((unsigned short)(tp >> 16));
            unsigned short o0 = f2bf(e0 + silu_(fmaf(t0, sc.x, sh.x)));
            unsigned short o1 = f2bf(e1 + silu_(fmaf(t1, sc.y, sh.y)));
            *(unsigned int*)(E + (size_t)j * D + c2) = ((unsigned int)o1 << 16) | o0;
            g = g2; ep = ep2; tp = tp2;
        }
    }
    float ic = inv_cnt[n];
    size_t o = (size_t)n * D + c2;
    float2 u = *(const float2*)(Uh + o);
    u.x = fmaf(a0, ic, u.x);
    u.y = fmaf(a1, ic, u.y);
    *(float2*)(Uh + o) = u;
}

// ---------- stats: partial reduce (no atomics) + merged finalize
__global__ __launch_bounds__(256) void reduceE_kernel(
    const float* __restrict__ P, int nblk, float* __restrict__ P2)
{
    int t = threadIdx.x;
    float s = 0.f;
    for (int j = blockIdx.x; j < nblk; j += gridDim.x)
        s += P[(size_t)j * 256 + t];
    P2[blockIdx.x * 256 + t] = s;
}

__global__ void finalize2_kernel(const float* __restrict__ P, int nblk,
                                 const float* __restrict__ gamma,
                                 const float* __restrict__ beta,
                                 float inv_rows, float* __restrict__ stats)
{
    int c = threadIdx.x;  // 128
    float s1 = 0.f, s2 = 0.f;
    for (int j = 0; j < nblk; ++j) {
        s1 += P[j * 256 + c];
        s2 += P[j * 256 + 128 + c];
    }
    float m = s1 * inv_rows;
    float v = s2 * inv_rows - m * m;
    float rstd = rsqrtf(v + BN_EPS);
    float sc = gamma[c] * rstd;
    stats[2 * D + c] = sc;
    stats[3 * D + c] = beta[c] - m * sc;
}

// ---------- input projections (init_h emits hi/lo too)
__global__ __launch_bounds__(256) void init_h_kernel(
    const float* __restrict__ x, const float* __restrict__ hp_w,
    const float* __restrict__ hp_b, float* __restrict__ h,
    unsigned short* __restrict__ hhi, unsigned short* __restrict__ hlo)
{
    int idx = blockIdx.x * 256 + threadIdx.x;
    int n = idx >> 5, d = (idx & 31) * 4;
    if (n >= NN) return;
    float x0 = x[n * 2], x1 = x[n * 2 + 1];
    float4 w0 = *(const float4*)(hp_w + d);
    float4 w1 = *(const float4*)(hp_w + D + d);
    float4 b = *(const float4*)(hp_b + d);
    float4 o;
    o.x = silu_(fmaf(x0, w0.x, fmaf(x1, w1.x, b.x)));
    o.y = silu_(fmaf(x0, w0.y, fmaf(x1, w1.y, b.y)));
    o.z = silu_(fmaf(x0, w0.z, fmaf(x1, w1.z, b.z)));
    o.w = silu_(fmaf(x0, w0.w, fmaf(x1, w1.w, b.w)));
    *(float4*)(h + (size_t)n * D + d) = o;
    ushort4 hi = make_ushort4(f2bf(o.x), f2bf(o.y), f2bf(o.z), f2bf(o.w));
    ushort4 lo = make_ushort4(f2bf(o.x - bf2f(hi.x)), f2bf(o.y - bf2f(hi.y)),
                              f2bf(o.z - bf2f(hi.z)), f2bf(o.w - bf2f(hi.w)));
    *(ushort4*)(hhi + (size_t)n * D + d) = hi;
    *(ushort4*)(hlo + (size_t)n * D + d) = lo;
}

// init_e in PERMUTED order: row j <- edge eidx[j]
__global__ __launch_bounds__(256) void init_e_kernel(
    const float* __restrict__ ea, const int* __restrict__ eidx,
    const float* __restrict__ ep_w, const float* __restrict__ ep_b,
    unsigned short* __restrict__ e)
{
    int idx = blockIdx.x * 256 + threadIdx.x;
    int j = idx >> 5, d = (idx & 31) * 4;
    if (j >= NE) return;
    float a = ea[eidx[j]];
    float4 w = *(const float4*)(ep_w + d);
    float4 b = *(const float4*)(ep_b + d);
    ushort4 o;
    o.x = f2bf(silu_(fmaf(a, w.x, b.x)));
    o.y = f2bf(silu_(fmaf(a, w.y, b.y)));
    o.z = f2bf(silu_(fmaf(a, w.z, b.z)));
    o.w = f2bf(silu_(fmaf(a, w.w, b.w)));
    *(ushort4*)(e + (size_t)j * D + d) = o;
}

// ---------- CSR build
__global__ __launch_bounds__(256) void deg_kernel(const int* __restrict__ src, int* __restrict__ deg)
{
    int i = blockIdx.x * 256 + threadIdx.x;
    if (i < NE) atomicAdd(&deg[src[i]], 1);
}

__global__ __launch_bounds__(256) void scan_kernel(
    const int* __restrict__ deg, int* __restrict__ rowptr, float* __restrict__ inv_cnt)
{
    __shared__ int chunk[256];
    const int t = threadIdx.x;
    const int CH = (NN + 255) / 256;
    int s = 0;
    for (int i = 0; i < CH; ++i) {
        int idx = t * CH + i;
        if (idx < NN) s += deg[idx];
    }
    chunk[t] = s;
    __syncthreads();
    for (int offs = 1; offs < 256; offs <<= 1) {
        int v = (t >= offs) ? chunk[t - offs] : 0;
        __syncthreads();
        chunk[t] += v;
        __syncthreads();
    }
    int base = (t == 0) ? 0 : chunk[t - 1];
    for (int i = 0; i < CH; ++i) {
        int idx = t * CH + i;
        if (idx < NN) {
            rowptr[idx] = base;
            int d = deg[idx];
            inv_cnt[idx] = 1.0f / fmaxf((float)d, 1.0f);
            base += d;
        }
    }
    if (t == 255) rowptr[NN] = base;
}

__global__ __launch_bounds__(256) void fill_kernel(
    const int* __restrict__ src, const int* __restrict__ dst,
    const int* __restrict__ rowptr, int* __restrict__ cursor,
    int* __restrict__ eidx, int* __restrict__ psrc, int* __restrict__ pdst)
{
    int i = blockIdx.x * 256 + threadIdx.x;
    if (i >= NE) return;
    int s = src[i];
    int p = atomicAdd(&cursor[s], 1);
    int pos = rowptr[s] + p;
    eidx[pos] = i;
    psrc[pos] = s;
    pdst[pos] = dst[i];
}

// column stats partials of fp32 t_h (exactly 20 blocks; no atomics)
__global__ __launch_bounds__(256) void colstats_h_kernel(
    const float* __restrict__ Th, float* __restrict__ PH)
{
    __shared__ float red1[8][128], red2[8][128];
    int t = threadIdx.x;
    int c0 = (t & 31) * 4, half = t >> 5;
    int rbase = blockIdx.x * 1024;
    float s1[4] = {0, 0, 0, 0}, s2[4] = {0, 0, 0, 0};
    for (int i = 0; i < 128; ++i) {
        int r = rbase + half + 8 * i;
        if (r >= NN) break;
        float4 v = *(const float4*)(Th + (size_t)r * D + c0);
        s1[0] += v.x; s2[0] = fmaf(v.x, v.x, s2[0]);
        s1[1] += v.y; s2[1] = fmaf(v.y, v.y, s2[1]);
        s1[2] += v.z; s2[2] = fmaf(v.z, v.z, s2[2]);
        s1[3] += v.w; s2[3] = fmaf(v.w, v.w, s2[3]);
    }
#pragma unroll
    for (int j = 0; j < 4; ++j) { red1[half][c0 + j] = s1[j]; red2[half][c0 + j] = s2[j]; }
    __syncthreads();
    if (t < 128) {
        float a = 0.f, b = 0.f;
#pragma unroll
        for (int hh = 0; hh < 8; ++hh) { a += red1[hh][t]; b += red2[hh][t]; }
        PH[(size_t)blockIdx.x * 256 + t] = a;
        PH[(size_t)blockIdx.x * 256 + 128 + t] = b;
    }
}

// h += silu(t_h*sc+sh); also emit h_hi/h_lo for next layer's node matmul
__global__ __launch_bounds__(256) void apply_h_kernel(
    float* __restrict__ h, const float* __restrict__ Th, const float* __restrict__ stats,
    unsigned short* __restrict__ hhi, unsigned short* __restrict__ hlo)
{
    int idx = blockIdx.x * 256 + threadIdx.x;
    int r = idx >> 5, d = (idx & 31) * 4;
    if (r >= NN) return;
    float4 tv = *(const float4*)(Th + (size_t)r * D + d);
    float4 sc = *(const float4*)(stats + 2 * D + d);
    float4 sh = *(const float4*)(stats + 3 * D + d);
    float4 hv = *(const float4*)(h + (size_t)r * D + d);
    hv.x += silu_(fmaf(tv.x, sc.x, sh.x));
    hv.y += silu_(fmaf(tv.y, sc.y, sh.y));
    hv.z += silu_(fmaf(tv.z, sc.z, sh.z));
    hv.w += silu_(fmaf(tv.w, sc.w, sh.w));
    *(float4*)(h + (size_t)r * D + d) = hv;
    ushort4 hi = make_ushort4(f2bf(hv.x), f2bf(hv.y), f2bf(hv.z), f2bf(hv.w));
    ushort4 lo = make_ushort4(f2bf(hv.x - bf2f(hi.x)), f2bf(hv.y - bf2f(hi.y)),
                              f2bf(hv.z - bf2f(hi.z)), f2bf(hv.w - bf2f(hi.w)));
    *(ushort4*)(hhi + (size_t)r * D + d) = hi;
    *(ushort4*)(hlo + (size_t)r * D + d) = lo;
}

extern "C" void kernel_launch(void* const* d_in, const int* in_sizes, int n_in,
                              void* d_out, int out_size, void* d_ws, size_t ws_size,
                              hipStream_t stream)
{
    (void)in_sizes; (void)n_in; (void)out_size;
    const float* x = (const float*)d_in[0];
    const float* edge_attr = (const float*)d_in[1];
    const int* edge_index = (const int*)d_in[2];
    const int* src = edge_index;
    const int* dst = edge_index + NE;
    const float* hp_w = (const float*)d_in[3];
    const float* hp_b = (const float*)d_in[4];
    const float* ep_w = (const float*)d_in[5];
    const float* ep_b = (const float*)d_in[6];
    const float* Uw = (const float*)d_in[7];
    const float* Ub = (const float*)d_in[8];
    const float* Vw = (const float*)d_in[9];
    const float* Vb = (const float*)d_in[10];
    const float* Aw = (const float*)d_in[11];
    const float* Ab = (const float*)d_in[12];
    const float* Bw = (const float*)d_in[13];
    const float* Bb = (const float*)d_in[14];
    const float* Cw = (const float*)d_in[15];
    const float* Cb = (const float*)d_in[16];
    const float* h_gamma = (const float*)d_in[17];
    const float* h_beta = (const float*)d_in[18];
    const float* e_gamma = (const float*)d_in[19];
    const float* e_beta = (const float*)d_in[20];
    const float* f1w = (const float*)d_in[21];
    const float* f1b = (const float*)d_in[22];
    const float* f2w = (const float*)d_in[23];
    const float* f2b = (const float*)d_in[24];
    const float* f3w = (const float*)d_in[25];
    const float* f3b = (const float*)d_in[26];
    float* out = (float*)d_out;

    size_t off = 0;
    auto alloc = [&](size_t nbytes) {
        void* p = (char*)d_ws + off;
        off += ((nbytes + 255) / 256) * 256;
        return p;
    };
    unsigned short* e_bf = (unsigned short*)alloc((size_t)NE * D * 2);
    unsigned short* t_bf = (unsigned short*)alloc((size_t)NE * D * 2);
    float* h  = (float*)alloc((size_t)NN * D * 4);
    unsigned short* h_hi = (unsigned short*)alloc((size_t)NN * D * 2);
    unsigned short* h_lo = (unsigned short*)alloc((size_t)NN * D * 2);
    float* Uh = (float*)alloc((size_t)NN * D * 4);
    float* Vh = (float*)alloc((size_t)NN * D * 4);
    float* Bh = (float*)alloc((size_t)NN * D * 4);
    float* Ch = (float*)alloc((size_t)NN * D * 4);
    int* deg = (int*)alloc(NN * 4);
    int* rowptr = (int*)alloc((NN + 1) * 4);
    int* cursor = (int*)alloc(NN * 4);
    int* eidx = (int*)alloc((size_t)NE * 4);
    int* psrc = (int*)alloc((size_t)NE * 4);
    int* pdst = (int*)alloc((size_t)NE * 4);
    float* inv_cnt = (float*)alloc(NN * 4);
    float* statsH = (float*)alloc(4 * D * 4);
    float* statsE = (float*)alloc(4 * D * 4);
    float* Pstats = (float*)alloc((size_t)(NE / 128) * 256 * 4);
    float* PstatsH = (float*)alloc(20 * 256 * 4);
    float* PE2 = (float*)alloc(64 * 256 * 4);
    unsigned short* wtsNhi = (unsigned short*)alloc((size_t)12 * D * D * 2);
    unsigned short* wtsNlo = (unsigned short*)alloc((size_t)12 * D * D * 2);
    unsigned short* wtsE = (unsigned short*)alloc((size_t)5 * D * D * 2);  // A0,A1,A2,F1,F2

    if (off > ws_size) return;  // diagnostic guard

    const int nodeBlocks32 = (NN * 32 + 255) / 256;  // 2500
    const int edgeBlocks32 = (NE * 32) / 256;        // 40000
    const int nodeTiles = (NN + 127) / 128;          // 157
    const int edgeTiles = NE / 128;                  // 2500
    const int hBlocks = (NN + 1023) / 1024;          // 20

    // CSR build (needed before permuted init_e)
    hipMemsetAsync(deg, 0, NN * sizeof(int), stream);
    hipMemsetAsync(cursor, 0, NN * sizeof(int), stream);
    deg_kernel<<<NE / 256, 256, 0, stream>>>(src, deg);
    scan_kernel<<<1, 256, 0, stream>>>(deg, rowptr, inv_cnt);
    fill_kernel<<<NE / 256, 256, 0, stream>>>(src, dst, rowptr, cursor, eidx, psrc, pdst);

    init_h_kernel<<<nodeBlocks32, 256, 0, stream>>>(x, hp_w, hp_b, h, h_hi, h_lo);
    init_e_kernel<<<edgeBlocks32, 256, 0, stream>>>(edge_attr, eidx, ep_w, ep_b, e_bf);

    // all 17 weight conversions in one dispatch
    ConvJobs cj;
    const float* nodeW[4][3] = {{Uw, Uw + 16384, Uw + 32768},
                                {Vw, Vw + 16384, Vw + 32768},
                                {Bw, Bw + 16384, Bw + 32768},
                                {Cw, Cw + 16384, Cw + 32768}};
    for (int l = 0; l < LAYERS; ++l)
        for (int j = 0; j < 4; ++j) {
            int slot = l * 4 + j;
            cj.W[slot] = nodeW[j][l];
            cj.Hi[slot] = wtsNhi + (size_t)slot * D * D;
            cj.Lo[slot] = wtsNlo + (size_t)slot * D * D;
        }
    const float* edgeW[5] = {Aw, Aw + 16384, Aw + 32768, f1w, f2w};
    for (int j = 0; j < 5; ++j) {
        cj.W[12 + j] = edgeW[j];
        cj.Hi[12 + j] = wtsE + (size_t)j * D * D;
        cj.Lo[12 + j] = nullptr;
    }
    conv_all_kernel<<<dim3(64, 17), 256, 0, stream>>>(cj);

    for (int l = 0; l < LAYERS; ++l) {
        const size_t bl = (size_t)l * D;

        MatsB2 m4;
        for (int j = 0; j < 4; ++j) {
            size_t slot = (size_t)(l * 4 + j) * D * D;
            m4.WThi[j] = wtsNhi + slot;
            m4.WTlo[j] = wtsNlo + slot;
        }
        m4.b[0] = Ub + bl; m4.b[1] = Vb + bl; m4.b[2] = Bb + bl; m4.b[3] = Cb + bl;
        m4.C[0] = Uh; m4.C[1] = Vh; m4.C[2] = Bh; m4.C[3] = Ch;
        mfmm_node_kernel<<<dim3(nodeTiles, 4), 256, 0, stream>>>(h_hi, h_lo, NN, m4);

        // t_e matmul + gathers + stat partials
        mfmm_te_kernel<<<edgeTiles, 256, 0, stream>>>(
            e_bf, wtsE + (size_t)l * D * D, Ab + bl, Bh, Ch, psrc, pdst, t_bf, Pstats);

        // e stats
        reduceE_kernel<<<64, 256, 0, stream>>>(Pstats, edgeTiles, PE2);
        finalize2_kernel<<<1, D, 0, stream>>>(PE2, 64, e_gamma + bl, e_beta + bl,
                                              1.0f / NE, statsE);

        // fused aggregation + e-update (all layers; e_bf fully updated after layer 2)
        agg_apply_kernel<<<(NN + 3) / 4, 256, 0, stream>>>(
            e_bf, t_bf, Vh, statsE, rowptr, pdst, inv_cnt, Uh);

        // h update (partials -> merged finalize)
        colstats_h_kernel<<<hBlocks, 256, 0, stream>>>(Uh, PstatsH);
        finalize2_kernel<<<1, D, 0, stream>>>(PstatsH, hBlocks, h_gamma + bl, h_beta + bl,
                                              1.0f / NN, statsH);
        apply_h_kernel<<<nodeBlocks32, 256, 0, stream>>>(h, Uh, statsH, h_hi, h_lo);
    }

    // fused final MLP: f1 + f2 + f3 (e_bf already holds final e state)
    mfmm_final_kernel<<<edgeTiles, 256, 0, stream>>>(
        e_bf,
        wtsE + (size_t)3 * D * D, f1b,
        wtsE + (size_t)4 * D * D, f2b,
        f3w, f3b, out, eidx);
}

// Round 19
// 966.949 us; speedup vs baseline: 1.2292x; 1.0029x over previous
//
#include <hip/hip_runtime.h>

#define NN 20000
#define NE 320000
#define D 128
#define LAYERS 3
#define BN_EPS 1e-5f

typedef __attribute__((ext_vector_type(8))) short s16x8;
typedef __attribute__((ext_vector_type(4))) float f32x4;

__device__ __forceinline__ float sigm_(float x) { return 1.0f / (1.0f + __expf(-x)); }
__device__ __forceinline__ float silu_(float x) { return x * sigm_(x); }
__device__ __forceinline__ float bf2f(unsigned short u) {
    union { unsigned int u; float f; } v; v.u = ((unsigned int)u) << 16; return v.f;
}
__device__ __forceinline__ unsigned short f2bf(float f) {
    union { float f; unsigned int u; } v; v.f = f;
    return (unsigned short)((v.u + 0x7FFFu + ((v.u >> 16) & 1u)) >> 16);
}

#define SWT_STRIDE 136

// ---------- all weight conversions in one dispatch: blockIdx.y = job
struct ConvJobs {
    const float* W[17];
    unsigned short* Hi[17];
    unsigned short* Lo[17];  // nullptr => single bf16 convert
};
__global__ __launch_bounds__(256) void conv_all_kernel(ConvJobs jobs)
{
    int y = blockIdx.y;
    int idx = blockIdx.x * 256 + threadIdx.x;  // 16384
    int k = idx >> 7, n = idx & 127;
    float v = jobs.W[y][idx];
    unsigned short hi = f2bf(v);
    jobs.Hi[y][n * 128 + k] = hi;
    if (jobs.Lo[y]) jobs.Lo[y][n * 128 + k] = f2bf(v - bf2f(hi));
}

struct MatsB2 {
    const unsigned short* WThi[4];
    const unsigned short* WTlo[4];
    const float* b[4];
    float* C[4];
};

// ---------- split-precision MFMA node matmul
__global__ __launch_bounds__(256, 2) void mfmm_node_kernel(
    const unsigned short* __restrict__ Ahi, const unsigned short* __restrict__ Alo,
    int M, MatsB2 ms)
{
    __shared__ unsigned short sW[128 * SWT_STRIDE];
    const int mat = blockIdx.y;
    const unsigned short* __restrict__ WThi = ms.WThi[mat];
    const unsigned short* __restrict__ WTlo = ms.WTlo[mat];
    const float* __restrict__ bias = ms.b[mat];
    float* __restrict__ C = ms.C[mat];
    const int t = threadIdx.x;
    const int w = t >> 6, lane = t & 63;
    const int q = lane >> 4, n = lane & 15;
    const int row0 = blockIdx.x * 128;

    int r0 = row0 + w * 32 + n;      if (r0 >= M) r0 = M - 1;
    int r1 = row0 + w * 32 + 16 + n; if (r1 >= M) r1 = M - 1;
    const size_t o0 = (size_t)r0 * D + q * 8;
    const size_t o1 = (size_t)r1 * D + q * 8;

    s16x8 ah[2][4], al[2][4];
#pragma unroll
    for (int kk = 0; kk < 4; ++kk) {
        ah[0][kk] = *(const s16x8*)(Ahi + o0 + kk * 32);
        ah[1][kk] = *(const s16x8*)(Ahi + o1 + kk * 32);
        al[0][kk] = *(const s16x8*)(Alo + o0 + kk * 32);
        al[1][kk] = *(const s16x8*)(Alo + o1 + kk * 32);
    }

    f32x4 acc[2][8];
#pragma unroll
    for (int tm = 0; tm < 2; ++tm)
#pragma unroll
        for (int tc = 0; tc < 8; ++tc) acc[tm][tc] = (f32x4){0.f, 0.f, 0.f, 0.f};

    // pass 1: W_hi (a_hi + a_lo)
#pragma unroll
    for (int i = 0; i < 8; ++i) {
        int flat = t * 8 + i * 2048;
        int r = flat >> 7, k = flat & 127;
        *(s16x8*)&sW[r * SWT_STRIDE + k] = *(const s16x8*)(WThi + flat);
    }
    __syncthreads();
#pragma unroll
    for (int kk = 0; kk < 4; ++kk) {
#pragma unroll
        for (int tc = 0; tc < 8; ++tc) {
            s16x8 bf = *(const s16x8*)&sW[(tc * 16 + n) * SWT_STRIDE + kk * 32 + q * 8];
            acc[0][tc] = __builtin_amdgcn_mfma_f32_16x16x32_bf16(ah[0][kk], bf, acc[0][tc], 0, 0, 0);
            acc[1][tc] = __builtin_amdgcn_mfma_f32_16x16x32_bf16(ah[1][kk], bf, acc[1][tc], 0, 0, 0);
            acc[0][tc] = __builtin_amdgcn_mfma_f32_16x16x32_bf16(al[0][kk], bf, acc[0][tc], 0, 0, 0);
            acc[1][tc] = __builtin_amdgcn_mfma_f32_16x16x32_bf16(al[1][kk], bf, acc[1][tc], 0, 0, 0);
        }
    }
    __syncthreads();

    // pass 2: W_lo (a_hi only)
#pragma unroll
    for (int i = 0; i < 8; ++i) {
        int flat = t * 8 + i * 2048;
        int r = flat >> 7, k = flat & 127;
        *(s16x8*)&sW[r * SWT_STRIDE + k] = *(const s16x8*)(WTlo + flat);
    }
    __syncthreads();
#pragma unroll
    for (int kk = 0; kk < 4; ++kk) {
#pragma unroll
        for (int tc = 0; tc < 8; ++tc) {
            s16x8 bf = *(const s16x8*)&sW[(tc * 16 + n) * SWT_STRIDE + kk * 32 + q * 8];
            acc[0][tc] = __builtin_amdgcn_mfma_f32_16x16x32_bf16(ah[0][kk], bf, acc[0][tc], 0, 0, 0);
            acc[1][tc] = __builtin_amdgcn_mfma_f32_16x16x32_bf16(ah[1][kk], bf, acc[1][tc], 0, 0, 0);
        }
    }

    float bs[8];
#pragma unroll
    for (int tc = 0; tc < 8; ++tc) bs[tc] = bias[tc * 16 + n];

#pragma unroll
    for (int tm = 0; tm < 2; ++tm)
#pragma unroll
        for (int r = 0; r < 4; ++r) {
            int row = row0 + w * 32 + tm * 16 + q * 4 + r;
            if (row >= M) continue;
#pragma unroll
            for (int tc = 0; tc < 8; ++tc)
                C[(size_t)row * D + tc * 16 + n] = acc[tm][tc][r] + bs[tc];
        }
}

// ---------- fused final MLP (dual LDS, 2 blocks/CU, e pre-updated by agg_apply)
__global__ __launch_bounds__(256, 2) void mfmm_final_kernel(
    const unsigned short* __restrict__ E,
    const unsigned short* __restrict__ WT1, const float* __restrict__ b1,
    const unsigned short* __restrict__ WT2, const float* __restrict__ b2,
    const float* __restrict__ f3w, const float* __restrict__ f3b,
    float* __restrict__ out, const int* __restrict__ perm)
{
    __shared__ unsigned short sW1[128 * SWT_STRIDE];
    __shared__ unsigned short sW2[128 * SWT_STRIDE];
    const int t = threadIdx.x;
    const int w = t >> 6, lane = t & 63;
    const int q = lane >> 4, n = lane & 15;
    const int row0 = blockIdx.x * 128;

#pragma unroll
    for (int i = 0; i < 8; ++i) {
        int flat = t * 8 + i * 2048;
        int r = flat >> 7, k = flat & 127;
        *(s16x8*)&sW1[r * SWT_STRIDE + k] = *(const s16x8*)(WT1 + flat);
    }
    __syncthreads();

    f32x4 acc[2][8];
#pragma unroll
    for (int tm = 0; tm < 2; ++tm)
#pragma unroll
        for (int tc = 0; tc < 8; ++tc) acc[tm][tc] = (f32x4){0.f, 0.f, 0.f, 0.f};

    const unsigned short* a0p = E + (size_t)(row0 + w * 32 + n) * D + q * 8;

#pragma unroll
    for (int kk = 0; kk < 128; kk += 32) {
        s16x8 af0 = *(const s16x8*)(a0p + kk);
        s16x8 af1 = *(const s16x8*)(a0p + 16 * D + kk);
#pragma unroll
        for (int tc = 0; tc < 8; ++tc) {
            s16x8 bf = *(const s16x8*)&sW1[(tc * 16 + n) * SWT_STRIDE + kk + q * 8];
            acc[0][tc] = __builtin_amdgcn_mfma_f32_16x16x32_bf16(af0, bf, acc[0][tc], 0, 0, 0);
            acc[1][tc] = __builtin_amdgcn_mfma_f32_16x16x32_bf16(af1, bf, acc[1][tc], 0, 0, 0);
        }
    }

    float bs1[8];
#pragma unroll
    for (int tc = 0; tc < 8; ++tc) bs1[tc] = b1[tc * 16 + n];
#pragma unroll
    for (int tm = 0; tm < 2; ++tm)
#pragma unroll
        for (int tc = 0; tc < 8; ++tc)
#pragma unroll
            for (int r = 0; r < 4; ++r) {
                int row = w * 32 + tm * 16 + q * 4 + r;
                int col = tc * 16 + n;
                sW2[row * SWT_STRIDE + col] = f2bf(silu_(acc[tm][tc][r] + bs1[tc]));
            }
    __syncthreads();

#pragma unroll
    for (int i = 0; i < 8; ++i) {
        int flat = t * 8 + i * 2048;
        int r = flat >> 7, k = flat & 127;
        *(s16x8*)&sW1[r * SWT_STRIDE + k] = *(const s16x8*)(WT2 + flat);
    }
    __syncthreads();

#pragma unroll
    for (int tm = 0; tm < 2; ++tm)
#pragma unroll
        for (int tc = 0; tc < 8; ++tc) acc[tm][tc] = (f32x4){0.f, 0.f, 0.f, 0.f};
#pragma unroll
    for (int kk = 0; kk < 128; kk += 32) {
        s16x8 af0 = *(const s16x8*)&sW2[(w * 32 + n) * SWT_STRIDE + kk + q * 8];
        s16x8 af1 = *(const s16x8*)&sW2[(w * 32 + 16 + n) * SWT_STRIDE + kk + q * 8];
#pragma unroll
        for (int tc = 0; tc < 8; ++tc) {
            s16x8 bf = *(const s16x8*)&sW1[(tc * 16 + n) * SWT_STRIDE + kk + q * 8];
            acc[0][tc] = __builtin_amdgcn_mfma_f32_16x16x32_bf16(af0, bf, acc[0][tc], 0, 0, 0);
            acc[1][tc] = __builtin_amdgcn_mfma_f32_16x16x32_bf16(af1, bf, acc[1][tc], 0, 0, 0);
        }
    }

    float bs2[8], f3v[8];
#pragma unroll
    for (int tc = 0; tc < 8; ++tc) {
        bs2[tc] = b2[tc * 16 + n];
        f3v[tc] = f3w[tc * 16 + n];
    }
    __syncthreads();
    float* red = (float*)sW2;  // [128][17]
#pragma unroll
    for (int tm = 0; tm < 2; ++tm)
#pragma unroll
        for (int r = 0; r < 4; ++r) {
            float p = 0.f;
#pragma unroll
            for (int tc = 0; tc < 8; ++tc)
                p = fmaf(silu_(acc[tm][tc][r] + bs2[tc]), f3v[tc], p);
            int row = w * 32 + tm * 16 + q * 4 + r;
            red[row * 17 + n] = p;
        }
    __syncthreads();
    if (t < 128) {
        float s = 0.f;
#pragma unroll
        for (int x = 0; x < 16; ++x) s += red[t * 17 + x];
        out[perm[row0 + t]] = sigm_(s + f3b[0]);
    }
}

// ---------- mfmm_te: t_e = e@Aw + Ab + Bh[psrc] + Ch[pdst] -> T, column stat partials
__global__ __launch_bounds__(256, 4) void mfmm_te_kernel(
    const unsigned short* __restrict__ A,   // e_bf (permuted order)
    const unsigned short* __restrict__ WT,
    const float* __restrict__ bias,
    const float* __restrict__ Bh, const float* __restrict__ Ch,
    const int* __restrict__ psrc, const int* __restrict__ pdst,
    unsigned short* __restrict__ T,
    float* __restrict__ P)
{
    __shared__ unsigned short sW[128 * SWT_STRIDE];
    const int t = threadIdx.x;
    const int w = t >> 6, lane = t & 63;
    const int q = lane >> 4, n = lane & 15;
    const int row0 = blockIdx.x * 128;

#pragma unroll
    for (int i = 0; i < 8; ++i) {
        int flat = t * 8 + i * 2048;
        int r = flat >> 7, k = flat & 127;
        *(s16x8*)&sW[r * SWT_STRIDE + k] = *(const s16x8*)(WT + flat);
    }
    __syncthreads();

    f32x4 acc[2][8];
#pragma unroll
    for (int tm = 0; tm < 2; ++tm)
#pragma unroll
        for (int tc = 0; tc < 8; ++tc) acc[tm][tc] = (f32x4){0.f, 0.f, 0.f, 0.f};

    const unsigned short* a0p = A + (size_t)(row0 + w * 32 + n) * D + q * 8;

#pragma unroll
    for (int kk = 0; kk < 128; kk += 32) {
        s16x8 af0 = *(const s16x8*)(a0p + kk);
        s16x8 af1 = *(const s16x8*)(a0p + 16 * D + kk);
#pragma unroll
        for (int tc = 0; tc < 8; ++tc) {
            s16x8 bf = *(const s16x8*)&sW[(tc * 16 + n) * SWT_STRIDE + kk + q * 8];
            acc[0][tc] = __builtin_amdgcn_mfma_f32_16x16x32_bf16(af0, bf, acc[0][tc], 0, 0, 0);
            acc[1][tc] = __builtin_amdgcn_mfma_f32_16x16x32_bf16(af1, bf, acc[1][tc], 0, 0, 0);
        }
    }

    float bs[8];
#pragma unroll
    for (int tc = 0; tc < 8; ++tc) bs[tc] = bias[tc * 16 + n];

    __syncthreads();
#pragma unroll
    for (int tm = 0; tm < 2; ++tm)
#pragma unroll
        for (int tc = 0; tc < 8; ++tc)
#pragma unroll
            for (int r = 0; r < 4; ++r) {
                int row = w * 32 + tm * 16 + q * 4 + r;
                int col = tc * 16 + n;
                sW[row * SWT_STRIDE + col] = f2bf(acc[tm][tc][r] + bs[tc]);
            }
    __syncthreads();

    const int c4 = (t & 31) * 4;
    const int rg = t >> 5;
    int srs[16], drs[16];
#pragma unroll
    for (int i = 0; i < 16; ++i) {
        int eid = row0 + rg + i * 8;
        srs[i] = psrc[eid];
        drs[i] = pdst[eid];
    }
    float s1[4] = {0.f, 0.f, 0.f, 0.f}, s2[4] = {0.f, 0.f, 0.f, 0.f};
#pragma unroll 8
    for (int i = 0; i < 16; ++i) {
        int row = rg + i * 8;
        int eid = row0 + row;
        float4 bv = *(const float4*)(Bh + (size_t)srs[i] * D + c4);
        float4 cv = *(const float4*)(Ch + (size_t)drs[i] * D + c4);
        ushort4 av = *(const ushort4*)&sW[row * SWT_STRIDE + c4];
        float t0 = bf2f(av.x) + bv.x + cv.x;
        float t1 = bf2f(av.y) + bv.y + cv.y;
        float t2 = bf2f(av.z) + bv.z + cv.z;
        float t3 = bf2f(av.w) + bv.w + cv.w;
        *(ushort4*)(T + (size_t)eid * D + c4) =
            make_ushort4(f2bf(t0), f2bf(t1), f2bf(t2), f2bf(t3));
        s1[0] += t0; s2[0] = fmaf(t0, t0, s2[0]);
        s1[1] += t1; s2[1] = fmaf(t1, t1, s2[1]);
        s1[2] += t2; s2[2] = fmaf(t2, t2, s2[2]);
        s1[3] += t3; s2[3] = fmaf(t3, t3, s2[3]);
    }
    __syncthreads();
    float* red = (float*)sW;
#pragma unroll
    for (int j = 0; j < 4; ++j) {
        red[rg * 128 + c4 + j] = s1[j];
        red[1024 + rg * 128 + c4 + j] = s2[j];
    }
    __syncthreads();
    if (t < 128) {
        float a = 0.f, b = 0.f;
#pragma unroll
        for (int g = 0; g < 8; ++g) { a += red[g * 128 + t]; b += red[1024 + g * 128 + t]; }
        P[(size_t)blockIdx.x * 256 + t] = a;
        P[(size_t)blockIdx.x * 256 + 128 + t] = b;
    }
}

// ---------- fused gather agg + apply_e (no atomics; independent waves; 2-deep pipeline:
// stage A prefetches indices/e/t for j+2, stage B issues Vh for j+1, consume j)
__global__ __launch_bounds__(256) void agg_apply_kernel(
    unsigned short* E, const unsigned short* __restrict__ T,
    const float* __restrict__ Vh, const float* __restrict__ stats,
    const int* __restrict__ rowptr, const int* __restrict__ pdst,
    const float* __restrict__ inv_cnt, float* __restrict__ Uh)
{
    int n = blockIdx.x * 4 + (threadIdx.x >> 6);
    if (n >= NN) return;
    int lane = threadIdx.x & 63;
    int c2 = lane * 2;
    float2 sc = *(const float2*)(stats + 2 * D + c2);
    float2 sh = *(const float2*)(stats + 3 * D + c2);
    int beg = rowptr[n], end = rowptr[n + 1];
    float a0 = 0.f, a1 = 0.f;

    if (beg < end) {
        // prologue: j=beg fully resolved; j=beg+1 indices loaded
        int g_nxt = 0;
        unsigned int ep_cur, tp_cur, ep_nxt = 0, tp_nxt = 0;
        ep_cur = *(const unsigned int*)(E + (size_t)beg * D + c2);
        tp_cur = *(const unsigned int*)(T + (size_t)beg * D + c2);
        int g0 = pdst[beg];
        if (beg + 1 < end) {
            g_nxt = pdst[beg + 1];
            ep_nxt = *(const unsigned int*)(E + (size_t)(beg + 1) * D + c2);
            tp_nxt = *(const unsigned int*)(T + (size_t)(beg + 1) * D + c2);
        }
        float2 vv_cur = *(const float2*)(Vh + (size_t)g0 * D + c2);

        for (int j = beg; j < end; ++j) {
            // stage A: prefetch indices/e/t for j+2
            int g2 = 0; unsigned int ep2 = 0, tp2 = 0;
            if (j + 2 < end) {
                g2 = pdst[j + 2];
                ep2 = *(const unsigned int*)(E + (size_t)(j + 2) * D + c2);
                tp2 = *(const unsigned int*)(T + (size_t)(j + 2) * D + c2);
            }
            // stage B: issue Vh gather for j+1 (index resolved last iteration)
            float2 vv_nxt = make_float2(0.f, 0.f);
            if (j + 1 < end)
                vv_nxt = *(const float2*)(Vh + (size_t)g_nxt * D + c2);
            // consume j
            float e0 = bf2f((unsigned short)(ep_cur & 0xffff));
            float e1 = bf2f((unsigned short)(ep_cur >> 16));
            a0 = fmaf(sigm_(e0), vv_cur.x, a0);
            a1 = fmaf(sigm_(e1), vv_cur.y, a1);
            float t0 = bf2f((unsigned short)(tp_cur & 0xffff));
            float t1 = bf2f((unsigned short)(tp_cur >> 16));
            unsigned short o0 = f2bf(e0 + silu_(fmaf(t0, sc.x, sh.x)));
            unsigned short o1 = f2bf(e1 + silu_(fmaf(t1, sc.y, sh.y)));
            *(unsigned int*)(E + (size_t)j * D + c2) = ((unsigned int)o1 << 16) | o0;
            // rotate pipeline
            ep_cur = ep_nxt; tp_cur = tp_nxt;
            ep_nxt = ep2; tp_nxt = tp2;
            g_nxt = g2;
            vv_cur = vv_nxt;
        }
    }
    float ic = inv_cnt[n];
    size_t o = (size_t)n * D + c2;
    float2 u = *(const float2*)(Uh + o);
    u.x = fmaf(a0, ic, u.x);
    u.y = fmaf(a1, ic, u.y);
    *(float2*)(Uh + o) = u;
}

// ---------- stats: partial reduce (no atomics) + merged finalize
__global__ __launch_bounds__(256) void reduceE_kernel(
    const float* __restrict__ P, int nblk, float* __restrict__ P2)
{
    int t = threadIdx.x;
    float s = 0.f;
    for (int j = blockIdx.x; j < nblk; j += gridDim.x)
        s += P[(size_t)j * 256 + t];
    P2[blockIdx.x * 256 + t] = s;
}

__global__ void finalize2_kernel(const float* __restrict__ P, int nblk,
                                 const float* __restrict__ gamma,
                                 const float* __restrict__ beta,
                                 float inv_rows, float* __restrict__ stats)
{
    int c = threadIdx.x;  // 128
    float s1 = 0.f, s2 = 0.f;
    for (int j = 0; j < nblk; ++j) {
        s1 += P[j * 256 + c];
        s2 += P[j * 256 + 128 + c];
    }
    float m = s1 * inv_rows;
    float v = s2 * inv_rows - m * m;
    float rstd = rsqrtf(v + BN_EPS);
    float sc = gamma[c] * rstd;
    stats[2 * D + c] = sc;
    stats[3 * D + c] = beta[c] - m * sc;
}

// ---------- input projections (init_h emits hi/lo too)
__global__ __launch_bounds__(256) void init_h_kernel(
    const float* __restrict__ x, const float* __restrict__ hp_w,
    const float* __restrict__ hp_b, float* __restrict__ h,
    unsigned short* __restrict__ hhi, unsigned short* __restrict__ hlo)
{
    int idx = blockIdx.x * 256 + threadIdx.x;
    int n = idx >> 5, d = (idx & 31) * 4;
    if (n >= NN) return;
    float x0 = x[n * 2], x1 = x[n * 2 + 1];
    float4 w0 = *(const float4*)(hp_w + d);
    float4 w1 = *(const float4*)(hp_w + D + d);
    float4 b = *(const float4*)(hp_b + d);
    float4 o;
    o.x = silu_(fmaf(x0, w0.x, fmaf(x1, w1.x, b.x)));
    o.y = silu_(fmaf(x0, w0.y, fmaf(x1, w1.y, b.y)));
    o.z = silu_(fmaf(x0, w0.z, fmaf(x1, w1.z, b.z)));
    o.w = silu_(fmaf(x0, w0.w, fmaf(x1, w1.w, b.w)));
    *(float4*)(h + (size_t)n * D + d) = o;
    ushort4 hi = make_ushort4(f2bf(o.x), f2bf(o.y), f2bf(o.z), f2bf(o.w));
    ushort4 lo = make_ushort4(f2bf(o.x - bf2f(hi.x)), f2bf(o.y - bf2f(hi.y)),
                              f2bf(o.z - bf2f(hi.z)), f2bf(o.w - bf2f(hi.w)));
    *(ushort4*)(hhi + (size_t)n * D + d) = hi;
    *(ushort4*)(hlo + (size_t)n * D + d) = lo;
}

// init_e in PERMUTED order: row j <- edge eidx[j]
__global__ __launch_bounds__(256) void init_e_kernel(
    const float* __restrict__ ea, const int* __restrict__ eidx,
    const float* __restrict__ ep_w, const float* __restrict__ ep_b,
    unsigned short* __restrict__ e)
{
    int idx = blockIdx.x * 256 + threadIdx.x;
    int j = idx >> 5, d = (idx & 31) * 4;
    if (j >= NE) return;
    float a = ea[eidx[j]];
    float4 w = *(const float4*)(ep_w + d);
    float4 b = *(const float4*)(ep_b + d);
    ushort4 o;
    o.x = f2bf(silu_(fmaf(a, w.x, b.x)));
    o.y = f2bf(silu_(fmaf(a, w.y, b.y)));
    o.z = f2bf(silu_(fmaf(a, w.z, b.z)));
    o.w = f2bf(silu_(fmaf(a, w.w, b.w)));
    *(ushort4*)(e + (size_t)j * D + d) = o;
}

// ---------- CSR build
__global__ __launch_bounds__(256) void deg_kernel(const int* __restrict__ src, int* __restrict__ deg)
{
    int i = blockIdx.x * 256 + threadIdx.x;
    if (i < NE) atomicAdd(&deg[src[i]], 1);
}

__global__ __launch_bounds__(256) void scan_kernel(
    const int* __restrict__ deg, int* __restrict__ rowptr, float* __restrict__ inv_cnt)
{
    __shared__ int chunk[256];
    const int t = threadIdx.x;
    const int CH = (NN + 255) / 256;
    int s = 0;
    for (int i = 0; i < CH; ++i) {
        int idx = t * CH + i;
        if (idx < NN) s += deg[idx];
    }
    chunk[t] = s;
    __syncthreads();
    for (int offs = 1; offs < 256; offs <<= 1) {
        int v = (t >= offs) ? chunk[t - offs] : 0;
        __syncthreads();
        chunk[t] += v;
        __syncthreads();
    }
    int base = (t == 0) ? 0 : chunk[t - 1];
    for (int i = 0; i < CH; ++i) {
        int idx = t * CH + i;
        if (idx < NN) {
            rowptr[idx] = base;
            int d = deg[idx];
            inv_cnt[idx] = 1.0f / fmaxf((float)d, 1.0f);
            base += d;
        }
    }
    if (t == 255) rowptr[NN] = base;
}

__global__ __launch_bounds__(256) void fill_kernel(
    const int* __restrict__ src, const int* __restrict__ dst,
    const int* __restrict__ rowptr, int* __restrict__ cursor,
    int* __restrict__ eidx, int* __restrict__ psrc, int* __restrict__ pdst)
{
    int i = blockIdx.x * 256 + threadIdx.x;
    if (i >= NE) return;
    int s = src[i];
    int p = atomicAdd(&cursor[s], 1);
    int pos = rowptr[s] + p;
    eidx[pos] = i;
    psrc[pos] = s;
    pdst[pos] = dst[i];
}

// column stats partials of fp32 t_h (exactly 20 blocks; no atomics)
__global__ __launch_bounds__(256) void colstats_h_kernel(
    const float* __restrict__ Th, float* __restrict__ PH)
{
    __shared__ float red1[8][128], red2[8][128];
    int t = threadIdx.x;
    int c0 = (t & 31) * 4, half = t >> 5;
    int rbase = blockIdx.x * 1024;
    float s1[4] = {0, 0, 0, 0}, s2[4] = {0, 0, 0, 0};
    for (int i = 0; i < 128; ++i) {
        int r = rbase + half + 8 * i;
        if (r >= NN) break;
        float4 v = *(const float4*)(Th + (size_t)r * D + c0);
        s1[0] += v.x; s2[0] = fmaf(v.x, v.x, s2[0]);
        s1[1] += v.y; s2[1] = fmaf(v.y, v.y, s2[1]);
        s1[2] += v.z; s2[2] = fmaf(v.z, v.z, s2[2]);
        s1[3] += v.w; s2[3] = fmaf(v.w, v.w, s2[3]);
    }
#pragma unroll
    for (int j = 0; j < 4; ++j) { red1[half][c0 + j] = s1[j]; red2[half][c0 + j] = s2[j]; }
    __syncthreads();
    if (t < 128) {
        float a = 0.f, b = 0.f;
#pragma unroll
        for (int hh = 0; hh < 8; ++hh) { a += red1[hh][t]; b += red2[hh][t]; }
        PH[(size_t)blockIdx.x * 256 + t] = a;
        PH[(size_t)blockIdx.x * 256 + 128 + t] = b;
    }
}

// h += silu(t_h*sc+sh); also emit h_hi/h_lo for next layer's node matmul
__global__ __launch_bounds__(256) void apply_h_kernel(
    float* __restrict__ h, const float* __restrict__ Th, const float* __restrict__ stats,
    unsigned short* __restrict__ hhi, unsigned short* __restrict__ hlo)
{
    int idx = blockIdx.x * 256 + threadIdx.x;
    int r = idx >> 5, d = (idx & 31) * 4;
    if (r >= NN) return;
    float4 tv = *(const float4*)(Th + (size_t)r * D + d);
    float4 sc = *(const float4*)(stats + 2 * D + d);
    float4 sh = *(const float4*)(stats + 3 * D + d);
    float4 hv = *(const float4*)(h + (size_t)r * D + d);
    hv.x += silu_(fmaf(tv.x, sc.x, sh.x));
    hv.y += silu_(fmaf(tv.y, sc.y, sh.y));
    hv.z += silu_(fmaf(tv.z, sc.z, sh.z));
    hv.w += silu_(fmaf(tv.w, sc.w, sh.w));
    *(float4*)(h + (size_t)r * D + d) = hv;
    ushort4 hi = make_ushort4(f2bf(hv.x), f2bf(hv.y), f2bf(hv.z), f2bf(hv.w));
    ushort4 lo = make_ushort4(f2bf(hv.x - bf2f(hi.x)), f2bf(hv.y - bf2f(hi.y)),
                              f2bf(hv.z - bf2f(hi.z)), f2bf(hv.w - bf2f(hi.w)));
    *(ushort4*)(hhi + (size_t)r * D + d) = hi;
    *(ushort4*)(hlo + (size_t)r * D + d) = lo;
}

extern "C" void kernel_launch(void* const* d_in, const int* in_sizes, int n_in,
                              void* d_out, int out_size, void* d_ws, size_t ws_size,
                              hipStream_t stream)
{
    (void)in_sizes; (void)n_in; (void)out_size;
    const float* x = (const float*)d_in[0];
    const float* edge_attr = (const float*)d_in[1];
    const int* edge_index = (const int*)d_in[2];
    const int* src = edge_index;
    const int* dst = edge_index + NE;
    const float* hp_w = (const float*)d_in[3];
    const float* hp_b = (const float*)d_in[4];
    const float* ep_w = (const float*)d_in[5];
    const float* ep_b = (const float*)d_in[6];
    const float* Uw = (const float*)d_in[7];
    const float* Ub = (const float*)d_in[8];
    const float* Vw = (const float*)d_in[9];
    const float* Vb = (const float*)d_in[10];
    const float* Aw = (const float*)d_in[11];
    const float* Ab = (const float*)d_in[12];
    const float* Bw = (const float*)d_in[13];
    const float* Bb = (const float*)d_in[14];
    const float* Cw = (const float*)d_in[15];
    const float* Cb = (const float*)d_in[16];
    const float* h_gamma = (const float*)d_in[17];
    const float* h_beta = (const float*)d_in[18];
    const float* e_gamma = (const float*)d_in[19];
    const float* e_beta = (const float*)d_in[20];
    const float* f1w = (const float*)d_in[21];
    const float* f1b = (const float*)d_in[22];
    const float* f2w = (const float*)d_in[23];
    const float* f2b = (const float*)d_in[24];
    const float* f3w = (const float*)d_in[25];
    const float* f3b = (const float*)d_in[26];
    float* out = (float*)d_out;

    size_t off = 0;
    auto alloc = [&](size_t nbytes) {
        void* p = (char*)d_ws + off;
        off += ((nbytes + 255) / 256) * 256;
        return p;
    };
    unsigned short* e_bf = (unsigned short*)alloc((size_t)NE * D * 2);
    unsigned short* t_bf = (unsigned short*)alloc((size_t)NE * D * 2);
    float* h  = (float*)alloc((size_t)NN * D * 4);
    unsigned short* h_hi = (unsigned short*)alloc((size_t)NN * D * 2);
    unsigned short* h_lo = (unsigned short*)alloc((size_t)NN * D * 2);
    float* Uh = (float*)alloc((size_t)NN * D * 4);
    float* Vh = (float*)alloc((size_t)NN * D * 4);
    float* Bh = (float*)alloc((size_t)NN * D * 4);
    float* Ch = (float*)alloc((size_t)NN * D * 4);
    int* deg = (int*)alloc(NN * 4);
    int* rowptr = (int*)alloc((NN + 1) * 4);
    int* cursor = (int*)alloc(NN * 4);
    int* eidx = (int*)alloc((size_t)NE * 4);
    int* psrc = (int*)alloc((size_t)NE * 4);
    int* pdst = (int*)alloc((size_t)NE * 4);
    float* inv_cnt = (float*)alloc(NN * 4);
    float* statsH = (float*)alloc(4 * D * 4);
    float* statsE = (float*)alloc(4 * D * 4);
    float* Pstats = (float*)alloc((size_t)(NE / 128) * 256 * 4);
    float* PstatsH = (float*)alloc(20 * 256 * 4);
    float* PE2 = (float*)alloc(64 * 256 * 4);
    unsigned short* wtsNhi = (unsigned short*)alloc((size_t)12 * D * D * 2);
    unsigned short* wtsNlo = (unsigned short*)alloc((size_t)12 * D * D * 2);
    unsigned short* wtsE = (unsigned short*)alloc((size_t)5 * D * D * 2);  // A0,A1,A2,F1,F2

    if (off > ws_size) return;  // diagnostic guard

    const int nodeBlocks32 = (NN * 32 + 255) / 256;  // 2500
    const int edgeBlocks32 = (NE * 32) / 256;        // 40000
    const int nodeTiles = (NN + 127) / 128;          // 157
    const int edgeTiles = NE / 128;                  // 2500
    const int hBlocks = (NN + 1023) / 1024;          // 20

    // CSR build (needed before permuted init_e)
    hipMemsetAsync(deg, 0, NN * sizeof(int), stream);
    hipMemsetAsync(cursor, 0, NN * sizeof(int), stream);
    deg_kernel<<<NE / 256, 256, 0, stream>>>(src, deg);
    scan_kernel<<<1, 256, 0, stream>>>(deg, rowptr, inv_cnt);
    fill_kernel<<<NE / 256, 256, 0, stream>>>(src, dst, rowptr, cursor, eidx, psrc, pdst);

    init_h_kernel<<<nodeBlocks32, 256, 0, stream>>>(x, hp_w, hp_b, h, h_hi, h_lo);
    init_e_kernel<<<edgeBlocks32, 256, 0, stream>>>(edge_attr, eidx, ep_w, ep_b, e_bf);

    // all 17 weight conversions in one dispatch
    ConvJobs cj;
    const float* nodeW[4][3] = {{Uw, Uw + 16384, Uw + 32768},
                                {Vw, Vw + 16384, Vw + 32768},
                                {Bw, Bw + 16384, Bw + 32768},
                                {Cw, Cw + 16384, Cw + 32768}};
    for (int l = 0; l < LAYERS; ++l)
        for (int j = 0; j < 4; ++j) {
            int slot = l * 4 + j;
            cj.W[slot] = nodeW[j][l];
            cj.Hi[slot] = wtsNhi + (size_t)slot * D * D;
            cj.Lo[slot] = wtsNlo + (size_t)slot * D * D;
        }
    const float* edgeW[5] = {Aw, Aw + 16384, Aw + 32768, f1w, f2w};
    for (int j = 0; j < 5; ++j) {
        cj.W[12 + j] = edgeW[j];
        cj.Hi[12 + j] = wtsE + (size_t)j * D * D;
        cj.Lo[12 + j] = nullptr;
    }
    conv_all_kernel<<<dim3(64, 17), 256, 0, stream>>>(cj);

    for (int l = 0; l < LAYERS; ++l) {
        const size_t bl = (size_t)l * D;

        MatsB2 m4;
        for (int j = 0; j < 4; ++j) {
            size_t slot = (size_t)(l * 4 + j) * D * D;
            m4.WThi[j] = wtsNhi + slot;
            m4.WTlo[j] = wtsNlo + slot;
        }
        m4.b[0] = Ub + bl; m4.b[1] = Vb + bl; m4.b[2] = Bb + bl; m4.b[3] = Cb + bl;
        m4.C[0] = Uh; m4.C[1] = Vh; m4.C[2] = Bh; m4.C[3] = Ch;
        mfmm_node_kernel<<<dim3(nodeTiles, 4), 256, 0, stream>>>(h_hi, h_lo, NN, m4);

        // t_e matmul + gathers + stat partials
        mfmm_te_kernel<<<edgeTiles, 256, 0, stream>>>(
            e_bf, wtsE + (size_t)l * D * D, Ab + bl, Bh, Ch, psrc, pdst, t_bf, Pstats);

        // e stats
        reduceE_kernel<<<64, 256, 0, stream>>>(Pstats, edgeTiles, PE2);
        finalize2_kernel<<<1, D, 0, stream>>>(PE2, 64, e_gamma + bl, e_beta + bl,
                                              1.0f / NE, statsE);

        // fused aggregation + e-update (all layers; e_bf fully updated after layer 2)
        agg_apply_kernel<<<(NN + 3) / 4, 256, 0, stream>>>(
            e_bf, t_bf, Vh, statsE, rowptr, pdst, inv_cnt, Uh);

        // h update (partials -> merged finalize)
        colstats_h_kernel<<<hBlocks, 256, 0, stream>>>(Uh, PstatsH);
        finalize2_kernel<<<1, D, 0, stream>>>(PstatsH, hBlocks, h_gamma + bl, h_beta + bl,
                                              1.0f / NN, statsH);
        apply_h_kernel<<<nodeBlocks32, 256, 0, stream>>>(h, Uh, statsH, h_hi, h_lo);
    }

    // fused final MLP: f1 + f2 + f3 (e_bf already holds final e state)
    mfmm_final_kernel<<<edgeTiles, 256, 0, stream>>>(
        e_bf,
        wtsE + (size_t)3 * D * D, f1b,
        wtsE + (size_t)4 * D * D, f2b,
        f3w, f3b, out, eidx);
}